// Round 9
// baseline (210.738 us; speedup 1.0000x reference)
//
#include <hip/hip_runtime.h>
#include <cmath>

// DDSP decoder, bit-exact-phase implementation.
// R9: MLP rebuilt as two tiled GEMM kernels (64x64 tiles, 4x4 regs/thread,
//     float4 weight loads, z/h tile in padded LDS). Weight L2 traffic
//     590MB -> ~35MB. Per-output op chain (bias, ascending-d fmaf, relu/
//     sigmoid) identical to the fused kernel -> amp/nmag bit-identical.
//     hp/hn intermediate aliases hpart (dead until k_harm).

#define NBATCH 8
#define NT     500
#define ND     128
#define TAUD   88000
#define NPART  64
#define NBINS  256
#define NFREQ  44001
#define LCONV  256

namespace {

constexpr float  SCALE_TA = (float)(500.0 / 88000.0);   // lin_interp scale, fp32 like jnp
constexpr float  SCALE_NF = (float)(256.0 / 44001.0);
constexpr float  TWOPI_F  = (float)6.283185307179586476925286766559;
constexpr float  CANG     = (float)(6.283185307179586476925286766559 / 88000.0);
constexpr float  INV_SR   = 1.0f / 44100.0f;            // RN reciprocal
constexpr float  INV2PI_F = 0.15915494309189535f;       // RN(1/2pi)
constexpr float  PI2_HI   = 6.2831854820251464844f;     // RN(2pi) fp32
constexpr float  PI2_LO   = -1.7484556000744487e-7f;    // RN(2pi - PI2_HI)

__device__ __forceinline__ void iparams(int j, int& i0, int& i1, float& w) {
  float jf  = (float)j;
  float src = __fsub_rn(__fmul_rn(__fadd_rn(jf, 0.5f), SCALE_TA), 0.5f);
  src = fminf(fmaxf(src, 0.0f), 499.0f);
  int a = (int)src;            // floor (src >= 0)
  i0 = a;
  i1 = (a + 1 > 499) ? 499 : (a + 1);
  w  = __fsub_rn(src, (float)a);
}

// correctly-rounded x/44100 (Markstein: RN recip + 2 fma) == __fdiv_rn
__device__ __forceinline__ float div_sr(float x) {
  float q0 = __fmul_rn(x, INV_SR);
  float e  = __builtin_fmaf(-44100.0f, q0, x);
  return __builtin_fmaf(e, INV_SR, q0);
}

__device__ __forceinline__ float inc_val(const float* sf0, int j, float pf) {
  int i0, i1; float w;
  iparams(j, i0, i1, w);
  float fa = __fmul_rn(sf0[i0], pf);
  float fb = __fmul_rn(sf0[i1], pf);
  float fu = __fadd_rn(__fmul_rn(fa, __fsub_rn(1.0f, w)), __fmul_rn(fb, w));
  return div_sr(fu);
}

// sin of the fp32 value x (|x| up to ~3e5): float Cody-Waite reduce + v_sin.
__device__ __forceinline__ float sin_fast(float x) {
  float k = rintf(__fmul_rn(x, INV2PI_F));
  float r = __builtin_fmaf(-k, PI2_HI, x);
  r = __builtin_fmaf(-k, PI2_LO, r);
  return __sinf(r);
}

// ---------------- f0 (Hz) ----------------
__global__ __launch_bounds__(256) void k_f0(const float* __restrict__ f0n,
                                            float* __restrict__ f0hz,
                                            float C1, float C2) {
  int i = blockIdx.x * 256 + threadIdx.x;
  if (i < NBATCH * NT) {
    float x = __fadd_rn(__fmul_rn(f0n[i], C1), C2);
    f0hz[i] = (float)exp2((double)x);
  }
}

// ---------------- MLP layer 1: hp/hn = relu(z @ W1{p,n} + b) ----------------
// 64 rows x 64 cols per block; thread (tx,ty) owns 4 cols x 4 rows.
__global__ __launch_bounds__(256) void k_mlp1(
    const float* __restrict__ z,
    const float* __restrict__ W1p, const float* __restrict__ b1p,
    const float* __restrict__ W1n, const float* __restrict__ b1n,
    float* __restrict__ hp, float* __restrict__ hn) {
  int ct = blockIdx.x;               // col tile 0..3
  int rt = blockIdx.y;               // row tile 0..62
  int tid = threadIdx.x;
  int tx = tid & 15, ty = tid >> 4;
  int col0 = ct * 64 + tx * 4;
  int row0 = rt * 64 + ty * 4;
  __shared__ float zs[64][129];      // padded: conflict-free column reads
  for (int i = tid; i < 64 * 32; i += 256) {
    int r = i >> 5, q = (i & 31) * 4;
    int gr = rt * 64 + r; if (gr > 3999) gr = 3999;
    float4 v = *(const float4*)&z[(size_t)gr * ND + q];
    zs[r][q] = v.x; zs[r][q + 1] = v.y; zs[r][q + 2] = v.z; zs[r][q + 3] = v.w;
  }
  __syncthreads();
  float accp[4][4], accn[4][4];
#pragma unroll
  for (int c = 0; c < 4; ++c) {
    float bp = b1p[col0 + c], bn = b1n[col0 + c];
#pragma unroll
    for (int r = 0; r < 4; ++r) { accp[r][c] = bp; accn[r][c] = bn; }
  }
#pragma unroll 2
  for (int d = 0; d < ND; ++d) {
    float4 wp = *(const float4*)&W1p[d * 256 + col0];
    float4 wn = *(const float4*)&W1n[d * 256 + col0];
    float zv[4];
#pragma unroll
    for (int r = 0; r < 4; ++r) zv[r] = zs[ty * 4 + r][d];
#pragma unroll
    for (int r = 0; r < 4; ++r) {
      accp[r][0] = fmaf(zv[r], wp.x, accp[r][0]);
      accp[r][1] = fmaf(zv[r], wp.y, accp[r][1]);
      accp[r][2] = fmaf(zv[r], wp.z, accp[r][2]);
      accp[r][3] = fmaf(zv[r], wp.w, accp[r][3]);
      accn[r][0] = fmaf(zv[r], wn.x, accn[r][0]);
      accn[r][1] = fmaf(zv[r], wn.y, accn[r][1]);
      accn[r][2] = fmaf(zv[r], wn.z, accn[r][2]);
      accn[r][3] = fmaf(zv[r], wn.w, accn[r][3]);
    }
  }
#pragma unroll
  for (int r = 0; r < 4; ++r) {
    int gr = row0 + r;
    if (gr < 4000) {
      float4 op = make_float4(fmaxf(accp[r][0], 0.0f), fmaxf(accp[r][1], 0.0f),
                              fmaxf(accp[r][2], 0.0f), fmaxf(accp[r][3], 0.0f));
      float4 on = make_float4(fmaxf(accn[r][0], 0.0f), fmaxf(accn[r][1], 0.0f),
                              fmaxf(accn[r][2], 0.0f), fmaxf(accn[r][3], 0.0f));
      *(float4*)&hp[(size_t)gr * 256 + col0] = op;
      *(float4*)&hn[(size_t)gr * 256 + col0] = on;
    }
  }
}

// ---------------- MLP layer 2: nmag = sigmoid(hn@W2n+b), amp = sigmoid(hp@W2p+b) ----
// blockIdx.x 0..3: nmag col tiles; 4: amp (64 cols). K=256 in two chunks.
__global__ __launch_bounds__(256) void k_mlp2(
    const float* __restrict__ hp, const float* __restrict__ hn,
    const float* __restrict__ W2p, const float* __restrict__ b2p,
    const float* __restrict__ W2n, const float* __restrict__ b2n,
    float* __restrict__ amp, float* __restrict__ nmag) {
  int ct = blockIdx.x;               // 0..4
  int rt = blockIdx.y;               // 0..62
  int tid = threadIdx.x;
  int tx = tid & 15, ty = tid >> 4;
  bool isAmp = (ct == 4);
  const float* hsrc = isAmp ? hp : hn;
  const float* Wsrc = isAmp ? W2p : W2n;
  const float* bias = isAmp ? b2p : b2n;
  int ncols = isAmp ? 64 : 256;
  int col0 = isAmp ? tx * 4 : ct * 64 + tx * 4;
  int row0 = rt * 64 + ty * 4;
  __shared__ float hs[64][129];
  float acc[4][4];
#pragma unroll
  for (int c = 0; c < 4; ++c) {
    float bv = bias[col0 + c];
#pragma unroll
    for (int r = 0; r < 4; ++r) acc[r][c] = bv;
  }
  for (int kc = 0; kc < 2; ++kc) {
    for (int i = tid; i < 64 * 32; i += 256) {
      int r = i >> 5, q = (i & 31) * 4;
      int gr = rt * 64 + r; if (gr > 3999) gr = 3999;
      float4 v = *(const float4*)&hsrc[(size_t)gr * 256 + kc * 128 + q];
      hs[r][q] = v.x; hs[r][q + 1] = v.y; hs[r][q + 2] = v.z; hs[r][q + 3] = v.w;
    }
    __syncthreads();
#pragma unroll 4
    for (int d = 0; d < 128; ++d) {
      float4 w = *(const float4*)&Wsrc[(size_t)(kc * 128 + d) * ncols + col0];
      float hv[4];
#pragma unroll
      for (int r = 0; r < 4; ++r) hv[r] = hs[ty * 4 + r][d];
#pragma unroll
      for (int r = 0; r < 4; ++r) {
        acc[r][0] = fmaf(hv[r], w.x, acc[r][0]);
        acc[r][1] = fmaf(hv[r], w.y, acc[r][1]);
        acc[r][2] = fmaf(hv[r], w.z, acc[r][2]);
        acc[r][3] = fmaf(hv[r], w.w, acc[r][3]);
      }
    }
    __syncthreads();
  }
#pragma unroll
  for (int r = 0; r < 4; ++r) {
    int gr = row0 + r;
    if (gr < 4000) {
      float4 o = make_float4(1.0f / (1.0f + expf(-acc[r][0])),
                             1.0f / (1.0f + expf(-acc[r][1])),
                             1.0f / (1.0f + expf(-acc[r][2])),
                             1.0f / (1.0f + expf(-acc[r][3])));
      if (isAmp) *(float4*)&amp[(size_t)gr * 64 + col0] = o;
      else       *(float4*)&nmag[(size_t)gr * 256 + col0] = o;
    }
  }
}

// ---------------- mean over frames (== mean of lin_interp, exact) ----------------
__global__ __launch_bounds__(256) void k_mean(const float* __restrict__ nmag,
                                              float* __restrict__ mm) {
  int b = blockIdx.x, k = threadIdx.x;
  float s = 0.0f;
  for (int t = 0; t < NT; ++t) s += nmag[((size_t)b * NT + t) * 256 + k];
  mm[b * 256 + k] = s * (1.0f / 500.0f);
}

// ---------------- basis G[n][i] = sum_k hat_i(k) * cos(2 pi n k / 88000) ----------------
__global__ __launch_bounds__(256) void k_basis(float* __restrict__ G) {
  int n = blockIdx.x;       // 0..LCONV
  int i = threadIdx.x;      // bin 0..255
  int start = 1, end = 43999;
  if (i > 0) {
    int s0 = (int)(((float)i - 0.5f) * 171.87890625f - 0.5f) - 4;
    if (s0 > start) start = s0;
  }
  int e0 = (int)(((float)i + 1.5f) * 171.87890625f - 0.5f) + 4;
  if (e0 < end) end = e0;
  float acc = 0.0f;
  int m = (n * start) % TAUD;
  for (int k = start; k <= end; ++k) {
    float kf  = (float)k;
    float src = __fsub_rn(__fmul_rn(__fadd_rn(kf, 0.5f), SCALE_NF), 0.5f);
    src = fminf(fmaxf(src, 0.0f), 255.0f);
    int i0 = (int)src;
    float w = __fsub_rn(src, (float)i0);
    float wt = 0.0f;
    if (i0 == i) wt = __fsub_rn(1.0f, w);
    int i1 = (i0 < 255) ? i0 + 1 : 255;
    if (i1 == i) wt = __fadd_rn(wt, w);
    acc = fmaf(wt, __cosf((float)m * CANG), acc);
    m += n; if (m >= TAUD) m -= TAUD;
  }
  G[n * 256 + i] = acc;
}

// ---------------- combine: h[b][n] = (F0 +- FN + 2*sum_i mm_i G[n][i]) / N ----------------
__global__ __launch_bounds__(256) void k_hc(const float* __restrict__ mm,
                                            const float* __restrict__ G,
                                            float* __restrict__ hh) {
  int n = blockIdx.x;       // 0..LCONV
  int tid = threadIdx.x;
  float g = G[n * 256 + tid];
  __shared__ float red[256];
  for (int b = 0; b < NBATCH; ++b) {
    red[tid] = mm[b * 256 + tid] * g;
    __syncthreads();
    for (int st = 128; st > 0; st >>= 1) {
      if (tid < st) red[tid] += red[tid + st];
      __syncthreads();
    }
    if (tid == 0) {
      float F0 = mm[b * 256 + 0];
      float src = __fsub_rn(__fmul_rn(__fadd_rn(44000.0f, 0.5f), SCALE_NF), 0.5f);
      src = fminf(fmaxf(src, 0.0f), 255.0f);
      int i0 = (int)src;
      float w = __fsub_rn(src, (float)i0);
      int i1 = (i0 < 255) ? i0 + 1 : 255;
      float FN = __fadd_rn(__fmul_rn(mm[b * 256 + i0], __fsub_rn(1.0f, w)),
                           __fmul_rn(mm[b * 256 + i1], w));
      float tot = 2.0f * red[0] + F0 + ((n & 1) ? -FN : FN);
      hh[b * (LCONV + 1) + n] = tot * (1.0f / 88000.0f);
    }
    __syncthreads();
  }
}

// ---------------- cumsum top levels: Brent-Kung (associative_scan DAG) ----------------
__global__ __launch_bounds__(256) void k_scan_top(const float* __restrict__ f0hz,
                                                  float* __restrict__ pref4) {
  int bp = blockIdx.x;
  int b = bp >> 6, p = bp & 63;
  float pf = (float)(p + 1);
  __shared__ float sf0[NT];
  __shared__ float lev[10992];
  int tid = threadIdx.x;
  for (int i = tid; i < NT; i += 256) sf0[i] = f0hz[b * NT + i];
  __syncthreads();
  for (int m = tid; m < 5500; m += 256) {
    float v[16];
#pragma unroll
    for (int t = 0; t < 16; ++t) v[t] = inc_val(sf0, m * 16 + t, pf);
    float s1[8];
#pragma unroll
    for (int t = 0; t < 8; ++t) s1[t] = __fadd_rn(v[2 * t], v[2 * t + 1]);
    float s2[4];
#pragma unroll
    for (int t = 0; t < 4; ++t) s2[t] = __fadd_rn(s1[2 * t], s1[2 * t + 1]);
    float s3a = __fadd_rn(s2[0], s2[1]);
    float s3b = __fadd_rn(s2[2], s2[3]);
    lev[m] = __fadd_rn(s3a, s3b);
  }
  __syncthreads();
  const int sizes[13] = {5500, 2750, 1375, 687, 343, 171, 85, 42, 21, 10, 5, 2, 1};
  const int offs[13]  = {0, 5500, 8250, 9625, 10312, 10655, 10826, 10911,
                         10953, 10974, 10984, 10989, 10991};
  for (int L = 1; L < 13; ++L) {
    int n = sizes[L];
    const float* src = lev + offs[L - 1];
    float* dst = lev + offs[L];
    for (int k2 = tid; k2 < n; k2 += 256)
      dst[k2] = __fadd_rn(src[2 * k2], src[2 * k2 + 1]);
    __syncthreads();
  }
  for (int L = 11; L >= 0; --L) {
    int n = sizes[L];
    float* cur = lev + offs[L];
    const float* up = lev + offs[L + 1];
    for (int idx = 1 + tid; idx < n; idx += 256) {
      float val;
      if (idx & 1) val = up[(idx - 1) >> 1];
      else         val = __fadd_rn(up[(idx >> 1) - 1], cur[idx]);
      cur[idx] = val;
    }
    __syncthreads();
  }
  for (int m = tid; m < 5500; m += 256)
    pref4[(size_t)bp * 5500 + m] = lev[m];
}

// ---------------- fused harmonic synth ----------------
__global__ __launch_bounds__(256) void k_harm(const float* __restrict__ f0hz,
                                              const float* __restrict__ amp,
                                              const float* __restrict__ pref4,
                                              float* __restrict__ hpart) {
  int chunk = blockIdx.x, b = blockIdx.y, g = blockIdx.z;
  int tid = threadIdx.x;
  int m = chunk * 256 + tid;
  bool act = (m < 5500);
  __shared__ float sf0[NT];
  for (int i = tid; i < NT; i += 256) sf0[i] = f0hz[b * NT + i];
  __syncthreads();
  int mm_ = act ? m : 0;
  int j0 = mm_ * 16;
  float wv[16], wm[16];
  unsigned damask = 0, dnmask = 0;
  int f = 0;
#pragma unroll
  for (int t = 0; t < 16; ++t) {
    int j = j0 + t;
    float jf = (float)j;
    float src = __fsub_rn(__fmul_rn(__fadd_rn(jf, 0.5f), SCALE_TA), 0.5f);
    src = fminf(fmaxf(src, 0.0f), 499.0f);
    int a = (int)src;
    if (t == 0) f = a;                 // i0 monotone nondecreasing in j
    wv[t] = __fsub_rn(src, (float)a);
    wm[t] = __fsub_rn(1.0f, wv[t]);
    damask |= (unsigned)(a - f) << t;  // in {0,1}
    int ni = (int)__fmul_rn(jf, SCALE_TA);
    ni = ni > 499 ? 499 : ni;
    dnmask |= (unsigned)(ni - f) << t; // in {0,1}
  }
  int f1 = (f + 1 > 499) ? 499 : f + 1;
  int f2 = (f + 2 > 499) ? 499 : f + 2;
  float s0 = sf0[f], s1 = sf0[f1], s2 = sf0[f2];

  float acc[16];
#pragma unroll
  for (int t = 0; t < 16; ++t) acc[t] = 0.0f;

  for (int pp = 0; pp < 16; ++pp) {
    int p = g * 16 + pp;
    float pf = (float)(p + 1);
    float fs0 = __fmul_rn(s0, pf);
    float fs1 = __fmul_rn(s1, pf);
    if (!(fs0 < 22050.0f) && !(fs1 < 22050.0f)) break;
    float fs2 = __fmul_rn(s2, pf);
    size_t pbase = ((size_t)(b * NPART + p)) * 5500;
    float left = (mm_ > 0) ? pref4[pbase + mm_ - 1] : 0.0f;
    float P4 = pref4[pbase + mm_];
    float v[16];
#pragma unroll
    for (int t = 0; t < 16; ++t) {
      bool d = (damask >> t) & 1;
      float fa = d ? fs1 : fs0;
      float fb = d ? fs2 : fs1;
      float fu = __fadd_rn(__fmul_rn(fa, wm[t]), __fmul_rn(fb, wv[t]));
      v[t] = div_sr(fu);
    }
    float s1t[8];
#pragma unroll
    for (int t = 0; t < 8; ++t) s1t[t] = __fadd_rn(v[2 * t], v[2 * t + 1]);
    float s2t[4];
#pragma unroll
    for (int t = 0; t < 4; ++t) s2t[t] = __fadd_rn(s1t[2 * t], s1t[2 * t + 1]);
    float s3_0 = __fadd_rn(s2t[0], s2t[1]);
    bool fz = (mm_ == 0);
    float l3_0 = fz ? s3_0 : __fadd_rn(left, s3_0);
    float l2_0 = fz ? s2t[0] : __fadd_rn(left, s2t[0]);
    float l2_1 = l3_0;
    float l2_2 = __fadd_rn(l3_0, s2t[2]);
    float l2_3 = P4;
    float l1_0 = fz ? s1t[0] : __fadd_rn(left, s1t[0]);
    float l1_1 = l2_0;
    float l1_2 = __fadd_rn(l2_0, s1t[2]);
    float l1_3 = l2_1;
    float l1_4 = __fadd_rn(l2_1, s1t[4]);
    float l1_5 = l2_2;
    float l1_6 = __fadd_rn(l2_2, s1t[6]);
    float l1_7 = l2_3;
    float ph[16];
    ph[0]  = fz ? v[0] : __fadd_rn(left, v[0]);
    ph[1]  = l1_0;
    ph[2]  = __fadd_rn(l1_0, v[2]);
    ph[3]  = l1_1;
    ph[4]  = __fadd_rn(l1_1, v[4]);
    ph[5]  = l1_2;
    ph[6]  = __fadd_rn(l1_2, v[6]);
    ph[7]  = l1_3;
    ph[8]  = __fadd_rn(l1_3, v[8]);
    ph[9]  = l1_4;
    ph[10] = __fadd_rn(l1_4, v[10]);
    ph[11] = l1_5;
    ph[12] = __fadd_rn(l1_5, v[12]);
    ph[13] = l1_6;
    ph[14] = __fadd_rn(l1_6, v[14]);
    ph[15] = l1_7;
    float ga0 = amp[((size_t)(b * NT + f)) * 64 + p];
    float ga1 = amp[((size_t)(b * NT + f1)) * 64 + p];
    float ga2 = amp[((size_t)(b * NT + f2)) * 64 + p];
#pragma unroll
    for (int t = 0; t < 16; ++t) {
      bool dn = (dnmask >> t) & 1;
      float fr = dn ? fs1 : fs0;
      if (fr < 22050.0f) {
        float x = __fmul_rn(ph[t], TWOPI_F);
        float s = sin_fast(x);
        bool d = (damask >> t) & 1;
        float lo = d ? ga1 : ga0;
        float hi = d ? ga2 : ga1;
        float au = __fadd_rn(__fmul_rn(lo, wm[t]), __fmul_rn(hi, wv[t]));
        acc[t] = __fadd_rn(acc[t], __fmul_rn(s, au));
      }
    }
  }
  if (act) {
    size_t obase = ((size_t)g * NBATCH + b) * TAUD + (size_t)j0;
#pragma unroll
    for (int t = 0; t < 16; ++t) hpart[obase + t] = acc[t];
  }
}

// ---------------- circular convolution (truncated +-LCONV=256) ----------------
#define CT    1024
#define PSTR  392
__global__ __launch_bounds__(256) void k_conv(const float* __restrict__ noise,
                                              const float* __restrict__ hh,
                                              float* __restrict__ ynz) {
  int b = blockIdx.y;
  int t0 = blockIdx.x * CT;
  int tid = threadIdx.x;
  __shared__ float xsp[4 * PSTR];     // window x[t0-256 .. t0+CT+256)
  __shared__ float hsh[LCONV];        // h[1..256]
  const float* hb = hh + b * (LCONV + 1);
  for (int i = tid; i < CT + 2 * LCONV; i += 256) {
    int j = t0 - LCONV + i;
    if (j < 0) j += TAUD;
    else if (j >= TAUD) j -= TAUD;
    xsp[(i & 3) * PSTR + (i >> 2)] = noise[(size_t)b * TAUD + j];
  }
  hsh[tid] = hb[1 + tid];             // LCONV == blockDim == 256
  __syncthreads();
  float h0 = hb[0];
  int B4 = tid + 64;                  // plane row of x[t0 + 4*tid]
  float a0 = h0 * xsp[0 * PSTR + B4];
  float a1 = h0 * xsp[1 * PSTR + B4];
  float a2 = h0 * xsp[2 * PSTR + B4];
  float a3 = h0 * xsp[3 * PSTR + B4];
  for (int g = 0; g < 32; ++g) {      // taps d = 8g+1 .. 8g+8
    int km = tid + 62 - 2 * g;        // minus side base (plane k)
    int kp = tid + 64 + 2 * g;        // plus side base
    float mv0 = xsp[0 * PSTR + km],     mv1 = xsp[1 * PSTR + km];
    float mv2 = xsp[2 * PSTR + km],     mv3 = xsp[3 * PSTR + km];
    float mv4 = xsp[0 * PSTR + km + 1], mv5 = xsp[1 * PSTR + km + 1];
    float mv6 = xsp[2 * PSTR + km + 1], mv7 = xsp[3 * PSTR + km + 1];
    float mv8 = xsp[0 * PSTR + km + 2], mv9 = xsp[1 * PSTR + km + 2];
    float mv10 = xsp[2 * PSTR + km + 2];
    float pv1 = xsp[1 * PSTR + kp],     pv2 = xsp[2 * PSTR + kp];
    float pv3 = xsp[3 * PSTR + kp];
    float pv4 = xsp[0 * PSTR + kp + 1], pv5 = xsp[1 * PSTR + kp + 1];
    float pv6 = xsp[2 * PSTR + kp + 1], pv7 = xsp[3 * PSTR + kp + 1];
    float pv8 = xsp[0 * PSTR + kp + 2], pv9 = xsp[1 * PSTR + kp + 2];
    float pv10 = xsp[2 * PSTR + kp + 2], pv11 = xsp[3 * PSTR + kp + 2];
    int hbase = 8 * g;                // uniform -> broadcast reads
    float hv0 = hsh[hbase + 0], hv1 = hsh[hbase + 1];
    float hv2 = hsh[hbase + 2], hv3 = hsh[hbase + 3];
    float hv4 = hsh[hbase + 4], hv5 = hsh[hbase + 5];
    float hv6 = hsh[hbase + 6], hv7 = hsh[hbase + 7];
    a0 = fmaf(hv0, mv7 + pv1, a0);
    a0 = fmaf(hv1, mv6 + pv2, a0);
    a0 = fmaf(hv2, mv5 + pv3, a0);
    a0 = fmaf(hv3, mv4 + pv4, a0);
    a0 = fmaf(hv4, mv3 + pv5, a0);
    a0 = fmaf(hv5, mv2 + pv6, a0);
    a0 = fmaf(hv6, mv1 + pv7, a0);
    a0 = fmaf(hv7, mv0 + pv8, a0);
    a1 = fmaf(hv0, mv8 + pv2, a1);
    a1 = fmaf(hv1, mv7 + pv3, a1);
    a1 = fmaf(hv2, mv6 + pv4, a1);
    a1 = fmaf(hv3, mv5 + pv5, a1);
    a1 = fmaf(hv4, mv4 + pv6, a1);
    a1 = fmaf(hv5, mv3 + pv7, a1);
    a1 = fmaf(hv6, mv2 + pv8, a1);
    a1 = fmaf(hv7, mv1 + pv9, a1);
    a2 = fmaf(hv0, mv9 + pv3, a2);
    a2 = fmaf(hv1, mv8 + pv4, a2);
    a2 = fmaf(hv2, mv7 + pv5, a2);
    a2 = fmaf(hv3, mv6 + pv6, a2);
    a2 = fmaf(hv4, mv5 + pv7, a2);
    a2 = fmaf(hv5, mv4 + pv8, a2);
    a2 = fmaf(hv6, mv3 + pv9, a2);
    a2 = fmaf(hv7, mv2 + pv10, a2);
    a3 = fmaf(hv0, mv10 + pv4, a3);
    a3 = fmaf(hv1, mv9 + pv5, a3);
    a3 = fmaf(hv2, mv8 + pv6, a3);
    a3 = fmaf(hv3, mv7 + pv7, a3);
    a3 = fmaf(hv4, mv6 + pv8, a3);
    a3 = fmaf(hv5, mv5 + pv9, a3);
    a3 = fmaf(hv6, mv4 + pv10, a3);
    a3 = fmaf(hv7, mv3 + pv11, a3);
  }
  int t = t0 + tid * 4;
  if (t < TAUD) {                     // TAUD%4==0 -> all 4 valid together
    float4 o = make_float4(a0 * 0.1f, a1 * 0.1f, a2 * 0.1f, a3 * 0.1f);
    *reinterpret_cast<float4*>(&ynz[(size_t)b * TAUD + t]) = o;
  }
}

// ---------------- final mix ----------------
__global__ __launch_bounds__(256) void k_final(const float* __restrict__ hpart,
                                               const float* __restrict__ ynz,
                                               const float* __restrict__ loud,
                                               float* __restrict__ out) {
  int idx = blockIdx.x * 256 + threadIdx.x;
  if (idx >= NBATCH * TAUD) return;
  int b = idx / TAUD, j = idx - b * TAUD;
  int i0, i1; float w;
  iparams(j, i0, i1, w);
  float env = __fadd_rn(__fmul_rn(loud[b * NT + i0], __fsub_rn(1.0f, w)),
                        __fmul_rn(loud[b * NT + i1], w));
  const size_t S = (size_t)NBATCH * TAUD;
  float hsum = __fadd_rn(__fadd_rn(__fadd_rn(hpart[idx], hpart[S + idx]),
                                   hpart[2 * S + idx]),
                         hpart[3 * S + idx]);
  out[idx] = __fmul_rn(__fadd_rn(hsum, ynz[idx]), env);
}

}  // namespace

extern "C" void kernel_launch(void* const* d_in, const int* in_sizes, int n_in,
                              void* d_out, int out_size, void* d_ws, size_t ws_size,
                              hipStream_t stream) {
  const float* z    = (const float*)d_in[0];
  const float* f0n  = (const float*)d_in[1];
  const float* loud = (const float*)d_in[2];
  const float* nz   = (const float*)d_in[3];
  const float* W1p  = (const float*)d_in[4];
  const float* b1p  = (const float*)d_in[5];
  const float* W2p  = (const float*)d_in[6];
  const float* b2p  = (const float*)d_in[7];
  const float* W1n  = (const float*)d_in[8];
  const float* b1n  = (const float*)d_in[9];
  const float* W2n  = (const float*)d_in[10];
  const float* b2n  = (const float*)d_in[11];
  float* out = (float*)d_out;
  float* ws  = (float*)d_ws;

  size_t off = 0;
  float* amp   = ws + off; off += (size_t)NBATCH * NT * NPART;      // 256,000
  float* nmag  = ws + off; off += (size_t)NBATCH * NT * NBINS;      // 1,024,000
  float* f0hz  = ws + off; off += (size_t)NBATCH * NT;              // 4,000
  float* mmw   = ws + off; off += (size_t)NBATCH * NBINS;           // 2,048
  float* G     = ws + off; off += (size_t)(LCONV + 1) * NBINS;      // 65,792
  float* hh    = ws + off; off += (size_t)NBATCH * (LCONV + 1);     // 2,056
  float* ynz   = ws + off; off += (size_t)NBATCH * TAUD;            // 704,000
  float* pref4 = ws + off; off += (size_t)NBATCH * NPART * 5500;    // 2,816,000
  float* hpart = ws + off; off += (size_t)4 * NBATCH * TAUD;        // 2,816,000
  (void)ws_size; (void)in_sizes; (void)n_in; (void)out_size;        // ~30 MB total

  // hp/hn alias hpart: consumed by k_mlp2 before k_harm overwrites hpart.
  float* hp = hpart;                      // 1,024,000 floats
  float* hn = hpart + (size_t)1024000;    // 1,024,000 floats (< 2,816,000)

  double HI = log2(2093.0), LO = log2(32.7);
  float C1 = (float)(HI - LO), C2 = (float)LO;

  k_basis<<<LCONV + 1, 256, 0, stream>>>(G);
  k_f0<<<(NBATCH * NT + 255) / 256, 256, 0, stream>>>(f0n, f0hz, C1, C2);
  dim3 g1(4, 63);
  k_mlp1<<<g1, 256, 0, stream>>>(z, W1p, b1p, W1n, b1n, hp, hn);
  dim3 g2(5, 63);
  k_mlp2<<<g2, 256, 0, stream>>>(hp, hn, W2p, b2p, W2n, b2n, amp, nmag);
  k_mean<<<NBATCH, 256, 0, stream>>>(nmag, mmw);
  k_hc<<<LCONV + 1, 256, 0, stream>>>(mmw, G, hh);
  k_scan_top<<<NBATCH * NPART, 256, 0, stream>>>(f0hz, pref4);
  dim3 gh(22, NBATCH, 4);
  k_harm<<<gh, 256, 0, stream>>>(f0hz, amp, pref4, hpart);
  dim3 gc((TAUD + CT - 1) / CT, NBATCH);
  k_conv<<<gc, 256, 0, stream>>>(nz, hh, ynz);
  k_final<<<(NBATCH * TAUD + 255) / 256, 256, 0, stream>>>(hpart, ynz, loud, out);
}

// Round 10
// 198.096 us; speedup vs baseline: 1.0638x; 1.0638x over previous
//
#include <hip/hip_runtime.h>
#include <cmath>

// DDSP decoder, bit-exact-phase implementation.
// R10: k_basis sliced over k into 4 sub-ranges (grid 257 -> 257x4 blocks;
//      was 1 block/CU, 6% occupancy, 41us for ~2us of work). k_hc sums the
//      4 partial G slices (ascending order). Everything else unchanged.

#define NBATCH 8
#define NT     500
#define ND     128
#define TAUD   88000
#define NPART  64
#define NBINS  256
#define NFREQ  44001
#define LCONV  256
#define BSLC   4

namespace {

constexpr float  SCALE_TA = (float)(500.0 / 88000.0);   // lin_interp scale, fp32 like jnp
constexpr float  SCALE_NF = (float)(256.0 / 44001.0);
constexpr float  TWOPI_F  = (float)6.283185307179586476925286766559;
constexpr float  CANG     = (float)(6.283185307179586476925286766559 / 88000.0);
constexpr float  INV_SR   = 1.0f / 44100.0f;            // RN reciprocal
constexpr float  INV2PI_F = 0.15915494309189535f;       // RN(1/2pi)
constexpr float  PI2_HI   = 6.2831854820251464844f;     // RN(2pi) fp32
constexpr float  PI2_LO   = -1.7484556000744487e-7f;    // RN(2pi - PI2_HI)

__device__ __forceinline__ void iparams(int j, int& i0, int& i1, float& w) {
  float jf  = (float)j;
  float src = __fsub_rn(__fmul_rn(__fadd_rn(jf, 0.5f), SCALE_TA), 0.5f);
  src = fminf(fmaxf(src, 0.0f), 499.0f);
  int a = (int)src;            // floor (src >= 0)
  i0 = a;
  i1 = (a + 1 > 499) ? 499 : (a + 1);
  w  = __fsub_rn(src, (float)a);
}

// correctly-rounded x/44100 (Markstein: RN recip + 2 fma) == __fdiv_rn
__device__ __forceinline__ float div_sr(float x) {
  float q0 = __fmul_rn(x, INV_SR);
  float e  = __builtin_fmaf(-44100.0f, q0, x);
  return __builtin_fmaf(e, INV_SR, q0);
}

__device__ __forceinline__ float inc_val(const float* sf0, int j, float pf) {
  int i0, i1; float w;
  iparams(j, i0, i1, w);
  float fa = __fmul_rn(sf0[i0], pf);
  float fb = __fmul_rn(sf0[i1], pf);
  float fu = __fadd_rn(__fmul_rn(fa, __fsub_rn(1.0f, w)), __fmul_rn(fb, w));
  return div_sr(fu);
}

// sin of the fp32 value x (|x| up to ~3e5): float Cody-Waite reduce + v_sin.
__device__ __forceinline__ float sin_fast(float x) {
  float k = rintf(__fmul_rn(x, INV2PI_F));
  float r = __builtin_fmaf(-k, PI2_HI, x);
  r = __builtin_fmaf(-k, PI2_LO, r);
  return __sinf(r);
}

// ---------------- f0 (Hz) ----------------
__global__ __launch_bounds__(256) void k_f0(const float* __restrict__ f0n,
                                            float* __restrict__ f0hz,
                                            float C1, float C2) {
  int i = blockIdx.x * 256 + threadIdx.x;
  if (i < NBATCH * NT) {
    float x = __fadd_rn(__fmul_rn(f0n[i], C1), C2);
    f0hz[i] = (float)exp2((double)x);
  }
}

// ---------------- MLP layer 1: hp/hn = relu(z @ W1{p,n} + b) ----------------
__global__ __launch_bounds__(256) void k_mlp1(
    const float* __restrict__ z,
    const float* __restrict__ W1p, const float* __restrict__ b1p,
    const float* __restrict__ W1n, const float* __restrict__ b1n,
    float* __restrict__ hp, float* __restrict__ hn) {
  int ct = blockIdx.x;               // col tile 0..3
  int rt = blockIdx.y;               // row tile 0..62
  int tid = threadIdx.x;
  int tx = tid & 15, ty = tid >> 4;
  int col0 = ct * 64 + tx * 4;
  int row0 = rt * 64 + ty * 4;
  __shared__ float zs[64][129];      // padded: conflict-free column reads
  for (int i = tid; i < 64 * 32; i += 256) {
    int r = i >> 5, q = (i & 31) * 4;
    int gr = rt * 64 + r; if (gr > 3999) gr = 3999;
    float4 v = *(const float4*)&z[(size_t)gr * ND + q];
    zs[r][q] = v.x; zs[r][q + 1] = v.y; zs[r][q + 2] = v.z; zs[r][q + 3] = v.w;
  }
  __syncthreads();
  float accp[4][4], accn[4][4];
#pragma unroll
  for (int c = 0; c < 4; ++c) {
    float bp = b1p[col0 + c], bn = b1n[col0 + c];
#pragma unroll
    for (int r = 0; r < 4; ++r) { accp[r][c] = bp; accn[r][c] = bn; }
  }
#pragma unroll 2
  for (int d = 0; d < ND; ++d) {
    float4 wp = *(const float4*)&W1p[d * 256 + col0];
    float4 wn = *(const float4*)&W1n[d * 256 + col0];
    float zv[4];
#pragma unroll
    for (int r = 0; r < 4; ++r) zv[r] = zs[ty * 4 + r][d];
#pragma unroll
    for (int r = 0; r < 4; ++r) {
      accp[r][0] = fmaf(zv[r], wp.x, accp[r][0]);
      accp[r][1] = fmaf(zv[r], wp.y, accp[r][1]);
      accp[r][2] = fmaf(zv[r], wp.z, accp[r][2]);
      accp[r][3] = fmaf(zv[r], wp.w, accp[r][3]);
      accn[r][0] = fmaf(zv[r], wn.x, accn[r][0]);
      accn[r][1] = fmaf(zv[r], wn.y, accn[r][1]);
      accn[r][2] = fmaf(zv[r], wn.z, accn[r][2]);
      accn[r][3] = fmaf(zv[r], wn.w, accn[r][3]);
    }
  }
#pragma unroll
  for (int r = 0; r < 4; ++r) {
    int gr = row0 + r;
    if (gr < 4000) {
      float4 op = make_float4(fmaxf(accp[r][0], 0.0f), fmaxf(accp[r][1], 0.0f),
                              fmaxf(accp[r][2], 0.0f), fmaxf(accp[r][3], 0.0f));
      float4 on = make_float4(fmaxf(accn[r][0], 0.0f), fmaxf(accn[r][1], 0.0f),
                              fmaxf(accn[r][2], 0.0f), fmaxf(accn[r][3], 0.0f));
      *(float4*)&hp[(size_t)gr * 256 + col0] = op;
      *(float4*)&hn[(size_t)gr * 256 + col0] = on;
    }
  }
}

// ---------------- MLP layer 2: nmag = sigmoid(hn@W2n+b), amp = sigmoid(hp@W2p+b) ----
__global__ __launch_bounds__(256) void k_mlp2(
    const float* __restrict__ hp, const float* __restrict__ hn,
    const float* __restrict__ W2p, const float* __restrict__ b2p,
    const float* __restrict__ W2n, const float* __restrict__ b2n,
    float* __restrict__ amp, float* __restrict__ nmag) {
  int ct = blockIdx.x;               // 0..4
  int rt = blockIdx.y;               // 0..62
  int tid = threadIdx.x;
  int tx = tid & 15, ty = tid >> 4;
  bool isAmp = (ct == 4);
  const float* hsrc = isAmp ? hp : hn;
  const float* Wsrc = isAmp ? W2p : W2n;
  const float* bias = isAmp ? b2p : b2n;
  int ncols = isAmp ? 64 : 256;
  int col0 = isAmp ? tx * 4 : ct * 64 + tx * 4;
  int row0 = rt * 64 + ty * 4;
  __shared__ float hs[64][129];
  float acc[4][4];
#pragma unroll
  for (int c = 0; c < 4; ++c) {
    float bv = bias[col0 + c];
#pragma unroll
    for (int r = 0; r < 4; ++r) acc[r][c] = bv;
  }
  for (int kc = 0; kc < 2; ++kc) {
    for (int i = tid; i < 64 * 32; i += 256) {
      int r = i >> 5, q = (i & 31) * 4;
      int gr = rt * 64 + r; if (gr > 3999) gr = 3999;
      float4 v = *(const float4*)&hsrc[(size_t)gr * 256 + kc * 128 + q];
      hs[r][q] = v.x; hs[r][q + 1] = v.y; hs[r][q + 2] = v.z; hs[r][q + 3] = v.w;
    }
    __syncthreads();
#pragma unroll 4
    for (int d = 0; d < 128; ++d) {
      float4 w = *(const float4*)&Wsrc[(size_t)(kc * 128 + d) * ncols + col0];
      float hv[4];
#pragma unroll
      for (int r = 0; r < 4; ++r) hv[r] = hs[ty * 4 + r][d];
#pragma unroll
      for (int r = 0; r < 4; ++r) {
        acc[r][0] = fmaf(hv[r], w.x, acc[r][0]);
        acc[r][1] = fmaf(hv[r], w.y, acc[r][1]);
        acc[r][2] = fmaf(hv[r], w.z, acc[r][2]);
        acc[r][3] = fmaf(hv[r], w.w, acc[r][3]);
      }
    }
    __syncthreads();
  }
#pragma unroll
  for (int r = 0; r < 4; ++r) {
    int gr = row0 + r;
    if (gr < 4000) {
      float4 o = make_float4(1.0f / (1.0f + expf(-acc[r][0])),
                             1.0f / (1.0f + expf(-acc[r][1])),
                             1.0f / (1.0f + expf(-acc[r][2])),
                             1.0f / (1.0f + expf(-acc[r][3])));
      if (isAmp) *(float4*)&amp[(size_t)gr * 64 + col0] = o;
      else       *(float4*)&nmag[(size_t)gr * 256 + col0] = o;
    }
  }
}

// ---------------- mean over frames (== mean of lin_interp, exact) ----------------
__global__ __launch_bounds__(256) void k_mean(const float* __restrict__ nmag,
                                              float* __restrict__ mm) {
  int b = blockIdx.x, k = threadIdx.x;
  float s = 0.0f;
  for (int t = 0; t < NT; ++t) s += nmag[((size_t)b * NT + t) * 256 + k];
  mm[b * 256 + k] = s * (1.0f / 500.0f);
}

// ---------------- basis G[s][n][i] = partial_s sum_k hat_i(k) cos(2 pi n k/88000) ----
// k-window sliced into BSLC contiguous sub-ranges (occupancy 1->4 blocks/CU).
__global__ __launch_bounds__(256) void k_basis(float* __restrict__ G) {
  int n = blockIdx.x;       // 0..LCONV
  int s = blockIdx.y;       // slice 0..BSLC-1
  int i = threadIdx.x;      // bin 0..255
  int start = 1, end = 43999;
  if (i > 0) {
    int s0 = (int)(((float)i - 0.5f) * 171.87890625f - 0.5f) - 4;
    if (s0 > start) start = s0;
  }
  int e0 = (int)(((float)i + 1.5f) * 171.87890625f - 0.5f) + 4;
  if (e0 < end) end = e0;
  int len = (end - start + BSLC) / BSLC;      // ceil
  int ks = start + s * len;
  int ke = ks + len - 1; if (ke > end) ke = end;
  float acc = 0.0f;
  if (ks <= ke) {
    int m = (int)(((long long)n * ks) % TAUD);
    for (int k = ks; k <= ke; ++k) {
      float kf  = (float)k;
      float src = __fsub_rn(__fmul_rn(__fadd_rn(kf, 0.5f), SCALE_NF), 0.5f);
      src = fminf(fmaxf(src, 0.0f), 255.0f);
      int i0 = (int)src;
      float w = __fsub_rn(src, (float)i0);
      float wt = 0.0f;
      if (i0 == i) wt = __fsub_rn(1.0f, w);
      int i1 = (i0 < 255) ? i0 + 1 : 255;
      if (i1 == i) wt = __fadd_rn(wt, w);
      acc = fmaf(wt, __cosf((float)m * CANG), acc);
      m += n; if (m >= TAUD) m -= TAUD;
    }
  }
  G[((size_t)s * (LCONV + 1) + n) * 256 + i] = acc;
}

// ---------------- combine: h[b][n] = (F0 +- FN + 2*sum_i mm_i G[n][i]) / N ----------------
__global__ __launch_bounds__(256) void k_hc(const float* __restrict__ mm,
                                            const float* __restrict__ G,
                                            float* __restrict__ hh) {
  int n = blockIdx.x;       // 0..LCONV
  int tid = threadIdx.x;
  const size_t GS = (size_t)(LCONV + 1) * 256;
  float g = ((G[(size_t)n * 256 + tid] + G[GS + (size_t)n * 256 + tid]) +
             (G[2 * GS + (size_t)n * 256 + tid] + G[3 * GS + (size_t)n * 256 + tid]));
  __shared__ float red[256];
  for (int b = 0; b < NBATCH; ++b) {
    red[tid] = mm[b * 256 + tid] * g;
    __syncthreads();
    for (int st = 128; st > 0; st >>= 1) {
      if (tid < st) red[tid] += red[tid + st];
      __syncthreads();
    }
    if (tid == 0) {
      float F0 = mm[b * 256 + 0];
      float src = __fsub_rn(__fmul_rn(__fadd_rn(44000.0f, 0.5f), SCALE_NF), 0.5f);
      src = fminf(fmaxf(src, 0.0f), 255.0f);
      int i0 = (int)src;
      float w = __fsub_rn(src, (float)i0);
      int i1 = (i0 < 255) ? i0 + 1 : 255;
      float FN = __fadd_rn(__fmul_rn(mm[b * 256 + i0], __fsub_rn(1.0f, w)),
                           __fmul_rn(mm[b * 256 + i1], w));
      float tot = 2.0f * red[0] + F0 + ((n & 1) ? -FN : FN);
      hh[b * (LCONV + 1) + n] = tot * (1.0f / 88000.0f);
    }
    __syncthreads();
  }
}

// ---------------- cumsum top levels: Brent-Kung (associative_scan DAG) ----------------
__global__ __launch_bounds__(256) void k_scan_top(const float* __restrict__ f0hz,
                                                  float* __restrict__ pref4) {
  int bp = blockIdx.x;
  int b = bp >> 6, p = bp & 63;
  float pf = (float)(p + 1);
  __shared__ float sf0[NT];
  __shared__ float lev[10992];
  int tid = threadIdx.x;
  for (int i = tid; i < NT; i += 256) sf0[i] = f0hz[b * NT + i];
  __syncthreads();
  for (int m = tid; m < 5500; m += 256) {
    float v[16];
#pragma unroll
    for (int t = 0; t < 16; ++t) v[t] = inc_val(sf0, m * 16 + t, pf);
    float s1[8];
#pragma unroll
    for (int t = 0; t < 8; ++t) s1[t] = __fadd_rn(v[2 * t], v[2 * t + 1]);
    float s2[4];
#pragma unroll
    for (int t = 0; t < 4; ++t) s2[t] = __fadd_rn(s1[2 * t], s1[2 * t + 1]);
    float s3a = __fadd_rn(s2[0], s2[1]);
    float s3b = __fadd_rn(s2[2], s2[3]);
    lev[m] = __fadd_rn(s3a, s3b);
  }
  __syncthreads();
  const int sizes[13] = {5500, 2750, 1375, 687, 343, 171, 85, 42, 21, 10, 5, 2, 1};
  const int offs[13]  = {0, 5500, 8250, 9625, 10312, 10655, 10826, 10911,
                         10953, 10974, 10984, 10989, 10991};
  for (int L = 1; L < 13; ++L) {
    int n = sizes[L];
    const float* src = lev + offs[L - 1];
    float* dst = lev + offs[L];
    for (int k2 = tid; k2 < n; k2 += 256)
      dst[k2] = __fadd_rn(src[2 * k2], src[2 * k2 + 1]);
    __syncthreads();
  }
  for (int L = 11; L >= 0; --L) {
    int n = sizes[L];
    float* cur = lev + offs[L];
    const float* up = lev + offs[L + 1];
    for (int idx = 1 + tid; idx < n; idx += 256) {
      float val;
      if (idx & 1) val = up[(idx - 1) >> 1];
      else         val = __fadd_rn(up[(idx >> 1) - 1], cur[idx]);
      cur[idx] = val;
    }
    __syncthreads();
  }
  for (int m = tid; m < 5500; m += 256)
    pref4[(size_t)bp * 5500 + m] = lev[m];
}

// ---------------- fused harmonic synth ----------------
__global__ __launch_bounds__(256) void k_harm(const float* __restrict__ f0hz,
                                              const float* __restrict__ amp,
                                              const float* __restrict__ pref4,
                                              float* __restrict__ hpart) {
  int chunk = blockIdx.x, b = blockIdx.y, g = blockIdx.z;
  int tid = threadIdx.x;
  int m = chunk * 256 + tid;
  bool act = (m < 5500);
  __shared__ float sf0[NT];
  for (int i = tid; i < NT; i += 256) sf0[i] = f0hz[b * NT + i];
  __syncthreads();
  int mm_ = act ? m : 0;
  int j0 = mm_ * 16;
  float wv[16], wm[16];
  unsigned damask = 0, dnmask = 0;
  int f = 0;
#pragma unroll
  for (int t = 0; t < 16; ++t) {
    int j = j0 + t;
    float jf = (float)j;
    float src = __fsub_rn(__fmul_rn(__fadd_rn(jf, 0.5f), SCALE_TA), 0.5f);
    src = fminf(fmaxf(src, 0.0f), 499.0f);
    int a = (int)src;
    if (t == 0) f = a;                 // i0 monotone nondecreasing in j
    wv[t] = __fsub_rn(src, (float)a);
    wm[t] = __fsub_rn(1.0f, wv[t]);
    damask |= (unsigned)(a - f) << t;  // in {0,1}
    int ni = (int)__fmul_rn(jf, SCALE_TA);
    ni = ni > 499 ? 499 : ni;
    dnmask |= (unsigned)(ni - f) << t; // in {0,1}
  }
  int f1 = (f + 1 > 499) ? 499 : f + 1;
  int f2 = (f + 2 > 499) ? 499 : f + 2;
  float s0 = sf0[f], s1 = sf0[f1], s2 = sf0[f2];

  float acc[16];
#pragma unroll
  for (int t = 0; t < 16; ++t) acc[t] = 0.0f;

  for (int pp = 0; pp < 16; ++pp) {
    int p = g * 16 + pp;
    float pf = (float)(p + 1);
    float fs0 = __fmul_rn(s0, pf);
    float fs1 = __fmul_rn(s1, pf);
    if (!(fs0 < 22050.0f) && !(fs1 < 22050.0f)) break;
    float fs2 = __fmul_rn(s2, pf);
    size_t pbase = ((size_t)(b * NPART + p)) * 5500;
    float left = (mm_ > 0) ? pref4[pbase + mm_ - 1] : 0.0f;
    float P4 = pref4[pbase + mm_];
    float v[16];
#pragma unroll
    for (int t = 0; t < 16; ++t) {
      bool d = (damask >> t) & 1;
      float fa = d ? fs1 : fs0;
      float fb = d ? fs2 : fs1;
      float fu = __fadd_rn(__fmul_rn(fa, wm[t]), __fmul_rn(fb, wv[t]));
      v[t] = div_sr(fu);
    }
    float s1t[8];
#pragma unroll
    for (int t = 0; t < 8; ++t) s1t[t] = __fadd_rn(v[2 * t], v[2 * t + 1]);
    float s2t[4];
#pragma unroll
    for (int t = 0; t < 4; ++t) s2t[t] = __fadd_rn(s1t[2 * t], s1t[2 * t + 1]);
    float s3_0 = __fadd_rn(s2t[0], s2t[1]);
    bool fz = (mm_ == 0);
    float l3_0 = fz ? s3_0 : __fadd_rn(left, s3_0);
    float l2_0 = fz ? s2t[0] : __fadd_rn(left, s2t[0]);
    float l2_1 = l3_0;
    float l2_2 = __fadd_rn(l3_0, s2t[2]);
    float l2_3 = P4;
    float l1_0 = fz ? s1t[0] : __fadd_rn(left, s1t[0]);
    float l1_1 = l2_0;
    float l1_2 = __fadd_rn(l2_0, s1t[2]);
    float l1_3 = l2_1;
    float l1_4 = __fadd_rn(l2_1, s1t[4]);
    float l1_5 = l2_2;
    float l1_6 = __fadd_rn(l2_2, s1t[6]);
    float l1_7 = l2_3;
    float ph[16];
    ph[0]  = fz ? v[0] : __fadd_rn(left, v[0]);
    ph[1]  = l1_0;
    ph[2]  = __fadd_rn(l1_0, v[2]);
    ph[3]  = l1_1;
    ph[4]  = __fadd_rn(l1_1, v[4]);
    ph[5]  = l1_2;
    ph[6]  = __fadd_rn(l1_2, v[6]);
    ph[7]  = l1_3;
    ph[8]  = __fadd_rn(l1_3, v[8]);
    ph[9]  = l1_4;
    ph[10] = __fadd_rn(l1_4, v[10]);
    ph[11] = l1_5;
    ph[12] = __fadd_rn(l1_5, v[12]);
    ph[13] = l1_6;
    ph[14] = __fadd_rn(l1_6, v[14]);
    ph[15] = l1_7;
    float ga0 = amp[((size_t)(b * NT + f)) * 64 + p];
    float ga1 = amp[((size_t)(b * NT + f1)) * 64 + p];
    float ga2 = amp[((size_t)(b * NT + f2)) * 64 + p];
#pragma unroll
    for (int t = 0; t < 16; ++t) {
      bool dn = (dnmask >> t) & 1;
      float fr = dn ? fs1 : fs0;
      if (fr < 22050.0f) {
        float x = __fmul_rn(ph[t], TWOPI_F);
        float s = sin_fast(x);
        bool d = (damask >> t) & 1;
        float lo = d ? ga1 : ga0;
        float hi = d ? ga2 : ga1;
        float au = __fadd_rn(__fmul_rn(lo, wm[t]), __fmul_rn(hi, wv[t]));
        acc[t] = __fadd_rn(acc[t], __fmul_rn(s, au));
      }
    }
  }
  if (act) {
    size_t obase = ((size_t)g * NBATCH + b) * TAUD + (size_t)j0;
#pragma unroll
    for (int t = 0; t < 16; ++t) hpart[obase + t] = acc[t];
  }
}

// ---------------- circular convolution (truncated +-LCONV=256) ----------------
#define CT    1024
#define PSTR  392
__global__ __launch_bounds__(256) void k_conv(const float* __restrict__ noise,
                                              const float* __restrict__ hh,
                                              float* __restrict__ ynz) {
  int b = blockIdx.y;
  int t0 = blockIdx.x * CT;
  int tid = threadIdx.x;
  __shared__ float xsp[4 * PSTR];     // window x[t0-256 .. t0+CT+256)
  __shared__ float hsh[LCONV];        // h[1..256]
  const float* hb = hh + b * (LCONV + 1);
  for (int i = tid; i < CT + 2 * LCONV; i += 256) {
    int j = t0 - LCONV + i;
    if (j < 0) j += TAUD;
    else if (j >= TAUD) j -= TAUD;
    xsp[(i & 3) * PSTR + (i >> 2)] = noise[(size_t)b * TAUD + j];
  }
  hsh[tid] = hb[1 + tid];             // LCONV == blockDim == 256
  __syncthreads();
  float h0 = hb[0];
  int B4 = tid + 64;                  // plane row of x[t0 + 4*tid]
  float a0 = h0 * xsp[0 * PSTR + B4];
  float a1 = h0 * xsp[1 * PSTR + B4];
  float a2 = h0 * xsp[2 * PSTR + B4];
  float a3 = h0 * xsp[3 * PSTR + B4];
  for (int g = 0; g < 32; ++g) {      // taps d = 8g+1 .. 8g+8
    int km = tid + 62 - 2 * g;        // minus side base (plane k)
    int kp = tid + 64 + 2 * g;        // plus side base
    float mv0 = xsp[0 * PSTR + km],     mv1 = xsp[1 * PSTR + km];
    float mv2 = xsp[2 * PSTR + km],     mv3 = xsp[3 * PSTR + km];
    float mv4 = xsp[0 * PSTR + km + 1], mv5 = xsp[1 * PSTR + km + 1];
    float mv6 = xsp[2 * PSTR + km + 1], mv7 = xsp[3 * PSTR + km + 1];
    float mv8 = xsp[0 * PSTR + km + 2], mv9 = xsp[1 * PSTR + km + 2];
    float mv10 = xsp[2 * PSTR + km + 2];
    float pv1 = xsp[1 * PSTR + kp],     pv2 = xsp[2 * PSTR + kp];
    float pv3 = xsp[3 * PSTR + kp];
    float pv4 = xsp[0 * PSTR + kp + 1], pv5 = xsp[1 * PSTR + kp + 1];
    float pv6 = xsp[2 * PSTR + kp + 1], pv7 = xsp[3 * PSTR + kp + 1];
    float pv8 = xsp[0 * PSTR + kp + 2], pv9 = xsp[1 * PSTR + kp + 2];
    float pv10 = xsp[2 * PSTR + kp + 2], pv11 = xsp[3 * PSTR + kp + 2];
    int hbase = 8 * g;                // uniform -> broadcast reads
    float hv0 = hsh[hbase + 0], hv1 = hsh[hbase + 1];
    float hv2 = hsh[hbase + 2], hv3 = hsh[hbase + 3];
    float hv4 = hsh[hbase + 4], hv5 = hsh[hbase + 5];
    float hv6 = hsh[hbase + 6], hv7 = hsh[hbase + 7];
    a0 = fmaf(hv0, mv7 + pv1, a0);
    a0 = fmaf(hv1, mv6 + pv2, a0);
    a0 = fmaf(hv2, mv5 + pv3, a0);
    a0 = fmaf(hv3, mv4 + pv4, a0);
    a0 = fmaf(hv4, mv3 + pv5, a0);
    a0 = fmaf(hv5, mv2 + pv6, a0);
    a0 = fmaf(hv6, mv1 + pv7, a0);
    a0 = fmaf(hv7, mv0 + pv8, a0);
    a1 = fmaf(hv0, mv8 + pv2, a1);
    a1 = fmaf(hv1, mv7 + pv3, a1);
    a1 = fmaf(hv2, mv6 + pv4, a1);
    a1 = fmaf(hv3, mv5 + pv5, a1);
    a1 = fmaf(hv4, mv4 + pv6, a1);
    a1 = fmaf(hv5, mv3 + pv7, a1);
    a1 = fmaf(hv6, mv2 + pv8, a1);
    a1 = fmaf(hv7, mv1 + pv9, a1);
    a2 = fmaf(hv0, mv9 + pv3, a2);
    a2 = fmaf(hv1, mv8 + pv4, a2);
    a2 = fmaf(hv2, mv7 + pv5, a2);
    a2 = fmaf(hv3, mv6 + pv6, a2);
    a2 = fmaf(hv4, mv5 + pv7, a2);
    a2 = fmaf(hv5, mv4 + pv8, a2);
    a2 = fmaf(hv6, mv3 + pv9, a2);
    a2 = fmaf(hv7, mv2 + pv10, a2);
    a3 = fmaf(hv0, mv10 + pv4, a3);
    a3 = fmaf(hv1, mv9 + pv5, a3);
    a3 = fmaf(hv2, mv8 + pv6, a3);
    a3 = fmaf(hv3, mv7 + pv7, a3);
    a3 = fmaf(hv4, mv6 + pv8, a3);
    a3 = fmaf(hv5, mv5 + pv9, a3);
    a3 = fmaf(hv6, mv4 + pv10, a3);
    a3 = fmaf(hv7, mv3 + pv11, a3);
  }
  int t = t0 + tid * 4;
  if (t < TAUD) {                     // TAUD%4==0 -> all 4 valid together
    float4 o = make_float4(a0 * 0.1f, a1 * 0.1f, a2 * 0.1f, a3 * 0.1f);
    *reinterpret_cast<float4*>(&ynz[(size_t)b * TAUD + t]) = o;
  }
}

// ---------------- final mix ----------------
__global__ __launch_bounds__(256) void k_final(const float* __restrict__ hpart,
                                               const float* __restrict__ ynz,
                                               const float* __restrict__ loud,
                                               float* __restrict__ out) {
  int idx = blockIdx.x * 256 + threadIdx.x;
  if (idx >= NBATCH * TAUD) return;
  int b = idx / TAUD, j = idx - b * TAUD;
  int i0, i1; float w;
  iparams(j, i0, i1, w);
  float env = __fadd_rn(__fmul_rn(loud[b * NT + i0], __fsub_rn(1.0f, w)),
                        __fmul_rn(loud[b * NT + i1], w));
  const size_t S = (size_t)NBATCH * TAUD;
  float hsum = __fadd_rn(__fadd_rn(__fadd_rn(hpart[idx], hpart[S + idx]),
                                   hpart[2 * S + idx]),
                         hpart[3 * S + idx]);
  out[idx] = __fmul_rn(__fadd_rn(hsum, ynz[idx]), env);
}

}  // namespace

extern "C" void kernel_launch(void* const* d_in, const int* in_sizes, int n_in,
                              void* d_out, int out_size, void* d_ws, size_t ws_size,
                              hipStream_t stream) {
  const float* z    = (const float*)d_in[0];
  const float* f0n  = (const float*)d_in[1];
  const float* loud = (const float*)d_in[2];
  const float* nz   = (const float*)d_in[3];
  const float* W1p  = (const float*)d_in[4];
  const float* b1p  = (const float*)d_in[5];
  const float* W2p  = (const float*)d_in[6];
  const float* b2p  = (const float*)d_in[7];
  const float* W1n  = (const float*)d_in[8];
  const float* b1n  = (const float*)d_in[9];
  const float* W2n  = (const float*)d_in[10];
  const float* b2n  = (const float*)d_in[11];
  float* out = (float*)d_out;
  float* ws  = (float*)d_ws;

  size_t off = 0;
  float* amp   = ws + off; off += (size_t)NBATCH * NT * NPART;          // 256,000
  float* nmag  = ws + off; off += (size_t)NBATCH * NT * NBINS;          // 1,024,000
  float* f0hz  = ws + off; off += (size_t)NBATCH * NT;                  // 4,000
  float* mmw   = ws + off; off += (size_t)NBATCH * NBINS;               // 2,048
  float* G     = ws + off; off += (size_t)BSLC * (LCONV + 1) * NBINS;   // 263,168
  float* hh    = ws + off; off += (size_t)NBATCH * (LCONV + 1);         // 2,056
  float* ynz   = ws + off; off += (size_t)NBATCH * TAUD;                // 704,000
  float* pref4 = ws + off; off += (size_t)NBATCH * NPART * 5500;        // 2,816,000
  float* hpart = ws + off; off += (size_t)4 * NBATCH * TAUD;            // 2,816,000
  (void)ws_size; (void)in_sizes; (void)n_in; (void)out_size;            // ~31 MB total

  // hp/hn alias hpart: consumed by k_mlp2 before k_harm overwrites hpart.
  float* hp = hpart;                      // 1,024,000 floats
  float* hn = hpart + (size_t)1024000;    // 1,024,000 floats (< 2,816,000)

  double HI = log2(2093.0), LO = log2(32.7);
  float C1 = (float)(HI - LO), C2 = (float)LO;

  dim3 gb(LCONV + 1, BSLC);
  k_basis<<<gb, 256, 0, stream>>>(G);
  k_f0<<<(NBATCH * NT + 255) / 256, 256, 0, stream>>>(f0n, f0hz, C1, C2);
  dim3 g1(4, 63);
  k_mlp1<<<g1, 256, 0, stream>>>(z, W1p, b1p, W1n, b1n, hp, hn);
  dim3 g2(5, 63);
  k_mlp2<<<g2, 256, 0, stream>>>(hp, hn, W2p, b2p, W2n, b2n, amp, nmag);
  k_mean<<<NBATCH, 256, 0, stream>>>(nmag, mmw);
  k_hc<<<LCONV + 1, 256, 0, stream>>>(mmw, G, hh);
  k_scan_top<<<NBATCH * NPART, 256, 0, stream>>>(f0hz, pref4);
  dim3 gh(22, NBATCH, 4);
  k_harm<<<gh, 256, 0, stream>>>(f0hz, amp, pref4, hpart);
  dim3 gc((TAUD + CT - 1) / CT, NBATCH);
  k_conv<<<gc, 256, 0, stream>>>(nz, hh, ynz);
  k_final<<<(NBATCH * TAUD + 255) / 256, 256, 0, stream>>>(hpart, ynz, loud, out);
}

// Round 11
// 192.564 us; speedup vs baseline: 1.0944x; 1.0287x over previous
//
#include <hip/hip_runtime.h>
#include <cmath>

// DDSP decoder, bit-exact-phase implementation.
// R11: scan split into k_lev4 (preamble amortized over 64 partials; was
//      recomputed per partial -- 315M of 600M ops) + k_scan_rest (the
//      unchanged Brent-Kung DAG on loaded lev4) -- values bit-identical.
//      k_basis BSLC 4->8 (occupancy). k_harm: fma for amp-interp/acc
//      (post-sin path only; phases untouched).

#define NBATCH 8
#define NT     500
#define ND     128
#define TAUD   88000
#define NPART  64
#define NBINS  256
#define NFREQ  44001
#define LCONV  256
#define BSLC   8

namespace {

constexpr float  SCALE_TA = (float)(500.0 / 88000.0);   // lin_interp scale, fp32 like jnp
constexpr float  SCALE_NF = (float)(256.0 / 44001.0);
constexpr float  TWOPI_F  = (float)6.283185307179586476925286766559;
constexpr float  CANG     = (float)(6.283185307179586476925286766559 / 88000.0);
constexpr float  INV_SR   = 1.0f / 44100.0f;            // RN reciprocal
constexpr float  INV2PI_F = 0.15915494309189535f;       // RN(1/2pi)
constexpr float  PI2_HI   = 6.2831854820251464844f;     // RN(2pi) fp32
constexpr float  PI2_LO   = -1.7484556000744487e-7f;    // RN(2pi - PI2_HI)

__device__ __forceinline__ void iparams(int j, int& i0, int& i1, float& w) {
  float jf  = (float)j;
  float src = __fsub_rn(__fmul_rn(__fadd_rn(jf, 0.5f), SCALE_TA), 0.5f);
  src = fminf(fmaxf(src, 0.0f), 499.0f);
  int a = (int)src;            // floor (src >= 0)
  i0 = a;
  i1 = (a + 1 > 499) ? 499 : (a + 1);
  w  = __fsub_rn(src, (float)a);
}

// correctly-rounded x/44100 (Markstein: RN recip + 2 fma) == __fdiv_rn
__device__ __forceinline__ float div_sr(float x) {
  float q0 = __fmul_rn(x, INV_SR);
  float e  = __builtin_fmaf(-44100.0f, q0, x);
  return __builtin_fmaf(e, INV_SR, q0);
}

// sin of the fp32 value x (|x| up to ~3e5): float Cody-Waite reduce + v_sin.
__device__ __forceinline__ float sin_fast(float x) {
  float k = rintf(__fmul_rn(x, INV2PI_F));
  float r = __builtin_fmaf(-k, PI2_HI, x);
  r = __builtin_fmaf(-k, PI2_LO, r);
  return __sinf(r);
}

// ---------------- f0 (Hz) ----------------
__global__ __launch_bounds__(256) void k_f0(const float* __restrict__ f0n,
                                            float* __restrict__ f0hz,
                                            float C1, float C2) {
  int i = blockIdx.x * 256 + threadIdx.x;
  if (i < NBATCH * NT) {
    float x = __fadd_rn(__fmul_rn(f0n[i], C1), C2);
    f0hz[i] = (float)exp2((double)x);
  }
}

// ---------------- MLP layer 1: hp/hn = relu(z @ W1{p,n} + b) ----------------
__global__ __launch_bounds__(256) void k_mlp1(
    const float* __restrict__ z,
    const float* __restrict__ W1p, const float* __restrict__ b1p,
    const float* __restrict__ W1n, const float* __restrict__ b1n,
    float* __restrict__ hp, float* __restrict__ hn) {
  int ct = blockIdx.x;               // col tile 0..3
  int rt = blockIdx.y;               // row tile 0..62
  int tid = threadIdx.x;
  int tx = tid & 15, ty = tid >> 4;
  int col0 = ct * 64 + tx * 4;
  int row0 = rt * 64 + ty * 4;
  __shared__ float zs[64][129];      // padded: conflict-free column reads
  for (int i = tid; i < 64 * 32; i += 256) {
    int r = i >> 5, q = (i & 31) * 4;
    int gr = rt * 64 + r; if (gr > 3999) gr = 3999;
    float4 v = *(const float4*)&z[(size_t)gr * ND + q];
    zs[r][q] = v.x; zs[r][q + 1] = v.y; zs[r][q + 2] = v.z; zs[r][q + 3] = v.w;
  }
  __syncthreads();
  float accp[4][4], accn[4][4];
#pragma unroll
  for (int c = 0; c < 4; ++c) {
    float bp = b1p[col0 + c], bn = b1n[col0 + c];
#pragma unroll
    for (int r = 0; r < 4; ++r) { accp[r][c] = bp; accn[r][c] = bn; }
  }
#pragma unroll 2
  for (int d = 0; d < ND; ++d) {
    float4 wp = *(const float4*)&W1p[d * 256 + col0];
    float4 wn = *(const float4*)&W1n[d * 256 + col0];
    float zv[4];
#pragma unroll
    for (int r = 0; r < 4; ++r) zv[r] = zs[ty * 4 + r][d];
#pragma unroll
    for (int r = 0; r < 4; ++r) {
      accp[r][0] = fmaf(zv[r], wp.x, accp[r][0]);
      accp[r][1] = fmaf(zv[r], wp.y, accp[r][1]);
      accp[r][2] = fmaf(zv[r], wp.z, accp[r][2]);
      accp[r][3] = fmaf(zv[r], wp.w, accp[r][3]);
      accn[r][0] = fmaf(zv[r], wn.x, accn[r][0]);
      accn[r][1] = fmaf(zv[r], wn.y, accn[r][1]);
      accn[r][2] = fmaf(zv[r], wn.z, accn[r][2]);
      accn[r][3] = fmaf(zv[r], wn.w, accn[r][3]);
    }
  }
#pragma unroll
  for (int r = 0; r < 4; ++r) {
    int gr = row0 + r;
    if (gr < 4000) {
      float4 op = make_float4(fmaxf(accp[r][0], 0.0f), fmaxf(accp[r][1], 0.0f),
                              fmaxf(accp[r][2], 0.0f), fmaxf(accp[r][3], 0.0f));
      float4 on = make_float4(fmaxf(accn[r][0], 0.0f), fmaxf(accn[r][1], 0.0f),
                              fmaxf(accn[r][2], 0.0f), fmaxf(accn[r][3], 0.0f));
      *(float4*)&hp[(size_t)gr * 256 + col0] = op;
      *(float4*)&hn[(size_t)gr * 256 + col0] = on;
    }
  }
}

// ---------------- MLP layer 2: nmag = sigmoid(hn@W2n+b), amp = sigmoid(hp@W2p+b) ----
__global__ __launch_bounds__(256) void k_mlp2(
    const float* __restrict__ hp, const float* __restrict__ hn,
    const float* __restrict__ W2p, const float* __restrict__ b2p,
    const float* __restrict__ W2n, const float* __restrict__ b2n,
    float* __restrict__ amp, float* __restrict__ nmag) {
  int ct = blockIdx.x;               // 0..4
  int rt = blockIdx.y;               // 0..62
  int tid = threadIdx.x;
  int tx = tid & 15, ty = tid >> 4;
  bool isAmp = (ct == 4);
  const float* hsrc = isAmp ? hp : hn;
  const float* Wsrc = isAmp ? W2p : W2n;
  const float* bias = isAmp ? b2p : b2n;
  int ncols = isAmp ? 64 : 256;
  int col0 = isAmp ? tx * 4 : ct * 64 + tx * 4;
  int row0 = rt * 64 + ty * 4;
  __shared__ float hs[64][129];
  float acc[4][4];
#pragma unroll
  for (int c = 0; c < 4; ++c) {
    float bv = bias[col0 + c];
#pragma unroll
    for (int r = 0; r < 4; ++r) acc[r][c] = bv;
  }
  for (int kc = 0; kc < 2; ++kc) {
    for (int i = tid; i < 64 * 32; i += 256) {
      int r = i >> 5, q = (i & 31) * 4;
      int gr = rt * 64 + r; if (gr > 3999) gr = 3999;
      float4 v = *(const float4*)&hsrc[(size_t)gr * 256 + kc * 128 + q];
      hs[r][q] = v.x; hs[r][q + 1] = v.y; hs[r][q + 2] = v.z; hs[r][q + 3] = v.w;
    }
    __syncthreads();
#pragma unroll 4
    for (int d = 0; d < 128; ++d) {
      float4 w = *(const float4*)&Wsrc[(size_t)(kc * 128 + d) * ncols + col0];
      float hv[4];
#pragma unroll
      for (int r = 0; r < 4; ++r) hv[r] = hs[ty * 4 + r][d];
#pragma unroll
      for (int r = 0; r < 4; ++r) {
        acc[r][0] = fmaf(hv[r], w.x, acc[r][0]);
        acc[r][1] = fmaf(hv[r], w.y, acc[r][1]);
        acc[r][2] = fmaf(hv[r], w.z, acc[r][2]);
        acc[r][3] = fmaf(hv[r], w.w, acc[r][3]);
      }
    }
    __syncthreads();
  }
#pragma unroll
  for (int r = 0; r < 4; ++r) {
    int gr = row0 + r;
    if (gr < 4000) {
      float4 o = make_float4(1.0f / (1.0f + expf(-acc[r][0])),
                             1.0f / (1.0f + expf(-acc[r][1])),
                             1.0f / (1.0f + expf(-acc[r][2])),
                             1.0f / (1.0f + expf(-acc[r][3])));
      if (isAmp) *(float4*)&amp[(size_t)gr * 64 + col0] = o;
      else       *(float4*)&nmag[(size_t)gr * 256 + col0] = o;
    }
  }
}

// ---------------- mean over frames (== mean of lin_interp, exact) ----------------
__global__ __launch_bounds__(256) void k_mean(const float* __restrict__ nmag,
                                              float* __restrict__ mm) {
  int b = blockIdx.x, k = threadIdx.x;
  float s = 0.0f;
  for (int t = 0; t < NT; ++t) s += nmag[((size_t)b * NT + t) * 256 + k];
  mm[b * 256 + k] = s * (1.0f / 500.0f);
}

// ---------------- basis G[s][n][i] = partial_s sum_k hat_i(k) cos(2 pi n k/88000) ----
__global__ __launch_bounds__(256) void k_basis(float* __restrict__ G) {
  int n = blockIdx.x;       // 0..LCONV
  int s = blockIdx.y;       // slice 0..BSLC-1
  int i = threadIdx.x;      // bin 0..255
  int start = 1, end = 43999;
  if (i > 0) {
    int s0 = (int)(((float)i - 0.5f) * 171.87890625f - 0.5f) - 4;
    if (s0 > start) start = s0;
  }
  int e0 = (int)(((float)i + 1.5f) * 171.87890625f - 0.5f) + 4;
  if (e0 < end) end = e0;
  int len = (end - start + BSLC) / BSLC;      // ceil
  int ks = start + s * len;
  int ke = ks + len - 1; if (ke > end) ke = end;
  float acc = 0.0f;
  if (ks <= ke) {
    int m = (int)(((long long)n * ks) % TAUD);
    for (int k = ks; k <= ke; ++k) {
      float kf  = (float)k;
      float src = __fsub_rn(__fmul_rn(__fadd_rn(kf, 0.5f), SCALE_NF), 0.5f);
      src = fminf(fmaxf(src, 0.0f), 255.0f);
      int i0 = (int)src;
      float w = __fsub_rn(src, (float)i0);
      float wt = 0.0f;
      if (i0 == i) wt = __fsub_rn(1.0f, w);
      int i1 = (i0 < 255) ? i0 + 1 : 255;
      if (i1 == i) wt = __fadd_rn(wt, w);
      acc = fmaf(wt, __cosf((float)m * CANG), acc);
      m += n; if (m >= TAUD) m -= TAUD;
    }
  }
  G[((size_t)s * (LCONV + 1) + n) * 256 + i] = acc;
}

// ---------------- combine: h[b][n] = (F0 +- FN + 2*sum_i mm_i G[n][i]) / N ----------------
__global__ __launch_bounds__(256) void k_hc(const float* __restrict__ mm,
                                            const float* __restrict__ G,
                                            float* __restrict__ hh) {
  int n = blockIdx.x;       // 0..LCONV
  int tid = threadIdx.x;
  const size_t GS = (size_t)(LCONV + 1) * 256;
  size_t gi = (size_t)n * 256 + tid;
  float g01 = G[gi] + G[GS + gi];
  float g23 = G[2 * GS + gi] + G[3 * GS + gi];
  float g45 = G[4 * GS + gi] + G[5 * GS + gi];
  float g67 = G[6 * GS + gi] + G[7 * GS + gi];
  float g = (g01 + g23) + (g45 + g67);
  __shared__ float red[256];
  for (int b = 0; b < NBATCH; ++b) {
    red[tid] = mm[b * 256 + tid] * g;
    __syncthreads();
    for (int st = 128; st > 0; st >>= 1) {
      if (tid < st) red[tid] += red[tid + st];
      __syncthreads();
    }
    if (tid == 0) {
      float F0 = mm[b * 256 + 0];
      float src = __fsub_rn(__fmul_rn(__fadd_rn(44000.0f, 0.5f), SCALE_NF), 0.5f);
      src = fminf(fmaxf(src, 0.0f), 255.0f);
      int i0 = (int)src;
      float w = __fsub_rn(src, (float)i0);
      int i1 = (i0 < 255) ? i0 + 1 : 255;
      float FN = __fadd_rn(__fmul_rn(mm[b * 256 + i0], __fsub_rn(1.0f, w)),
                           __fmul_rn(mm[b * 256 + i1], w));
      float tot = 2.0f * red[0] + F0 + ((n & 1) ? -FN : FN);
      hh[b * (LCONV + 1) + n] = tot * (1.0f / 88000.0f);
    }
    __syncthreads();
  }
}

// ---------------- level-4 block sums (preamble amortized over 64 partials) ----------
// Same select-based v[] + pair tree as k_harm (bit-identical to inc_val chain).
__global__ __launch_bounds__(256) void k_lev4(const float* __restrict__ f0hz,
                                              float* __restrict__ lev4) {
  int chunk = blockIdx.x, b = blockIdx.y;
  int tid = threadIdx.x;
  int m = chunk * 256 + tid;
  bool act = (m < 5500);
  __shared__ float sf0[NT];
  for (int i = tid; i < NT; i += 256) sf0[i] = f0hz[b * NT + i];
  __syncthreads();
  if (!act) return;
  int j0 = m * 16;
  float wv[16], wm[16];
  unsigned damask = 0;
  int f = 0;
#pragma unroll
  for (int t = 0; t < 16; ++t) {
    int j = j0 + t;
    float jf = (float)j;
    float src = __fsub_rn(__fmul_rn(__fadd_rn(jf, 0.5f), SCALE_TA), 0.5f);
    src = fminf(fmaxf(src, 0.0f), 499.0f);
    int a = (int)src;
    if (t == 0) f = a;
    wv[t] = __fsub_rn(src, (float)a);
    wm[t] = __fsub_rn(1.0f, wv[t]);
    damask |= (unsigned)(a - f) << t;
  }
  int f1 = (f + 1 > 499) ? 499 : f + 1;
  int f2 = (f + 2 > 499) ? 499 : f + 2;
  float s0 = sf0[f], s1 = sf0[f1], s2 = sf0[f2];
  for (int p = 0; p < NPART; ++p) {
    float pf = (float)(p + 1);
    float fs0 = __fmul_rn(s0, pf);
    float fs1 = __fmul_rn(s1, pf);
    float fs2 = __fmul_rn(s2, pf);
    float v[16];
#pragma unroll
    for (int t = 0; t < 16; ++t) {
      bool d = (damask >> t) & 1;
      float fa = d ? fs1 : fs0;
      float fb = d ? fs2 : fs1;
      float fu = __fadd_rn(__fmul_rn(fa, wm[t]), __fmul_rn(fb, wv[t]));
      v[t] = div_sr(fu);
    }
    float s1t[8];
#pragma unroll
    for (int t = 0; t < 8; ++t) s1t[t] = __fadd_rn(v[2 * t], v[2 * t + 1]);
    float s2t[4];
#pragma unroll
    for (int t = 0; t < 4; ++t) s2t[t] = __fadd_rn(s1t[2 * t], s1t[2 * t + 1]);
    float s3a = __fadd_rn(s2t[0], s2t[1]);
    float s3b = __fadd_rn(s2t[2], s2t[3]);
    lev4[((size_t)(b * NPART + p)) * 5500 + m] = __fadd_rn(s3a, s3b);
  }
}

// ---------------- scan upper levels: Brent-Kung on loaded lev4 ----------------
__global__ __launch_bounds__(256) void k_scan_rest(const float* __restrict__ lev4,
                                                   float* __restrict__ pref4) {
  int bp = blockIdx.x;
  __shared__ float lev[10992];
  int tid = threadIdx.x;
  for (int m = tid; m < 5500; m += 256) lev[m] = lev4[(size_t)bp * 5500 + m];
  __syncthreads();
  const int sizes[13] = {5500, 2750, 1375, 687, 343, 171, 85, 42, 21, 10, 5, 2, 1};
  const int offs[13]  = {0, 5500, 8250, 9625, 10312, 10655, 10826, 10911,
                         10953, 10974, 10984, 10989, 10991};
  for (int L = 1; L < 13; ++L) {
    int n = sizes[L];
    const float* src = lev + offs[L - 1];
    float* dst = lev + offs[L];
    for (int k2 = tid; k2 < n; k2 += 256)
      dst[k2] = __fadd_rn(src[2 * k2], src[2 * k2 + 1]);
    __syncthreads();
  }
  for (int L = 11; L >= 0; --L) {
    int n = sizes[L];
    float* cur = lev + offs[L];
    const float* up = lev + offs[L + 1];
    for (int idx = 1 + tid; idx < n; idx += 256) {
      float val;
      if (idx & 1) val = up[(idx - 1) >> 1];
      else         val = __fadd_rn(up[(idx >> 1) - 1], cur[idx]);
      cur[idx] = val;
    }
    __syncthreads();
  }
  for (int m = tid; m < 5500; m += 256)
    pref4[(size_t)bp * 5500 + m] = lev[m];
}

// ---------------- fused harmonic synth ----------------
__global__ __launch_bounds__(256) void k_harm(const float* __restrict__ f0hz,
                                              const float* __restrict__ amp,
                                              const float* __restrict__ pref4,
                                              float* __restrict__ hpart) {
  int chunk = blockIdx.x, b = blockIdx.y, g = blockIdx.z;
  int tid = threadIdx.x;
  int m = chunk * 256 + tid;
  bool act = (m < 5500);
  __shared__ float sf0[NT];
  for (int i = tid; i < NT; i += 256) sf0[i] = f0hz[b * NT + i];
  __syncthreads();
  int mm_ = act ? m : 0;
  int j0 = mm_ * 16;
  float wv[16], wm[16];
  unsigned damask = 0, dnmask = 0;
  int f = 0;
#pragma unroll
  for (int t = 0; t < 16; ++t) {
    int j = j0 + t;
    float jf = (float)j;
    float src = __fsub_rn(__fmul_rn(__fadd_rn(jf, 0.5f), SCALE_TA), 0.5f);
    src = fminf(fmaxf(src, 0.0f), 499.0f);
    int a = (int)src;
    if (t == 0) f = a;                 // i0 monotone nondecreasing in j
    wv[t] = __fsub_rn(src, (float)a);
    wm[t] = __fsub_rn(1.0f, wv[t]);
    damask |= (unsigned)(a - f) << t;  // in {0,1}
    int ni = (int)__fmul_rn(jf, SCALE_TA);
    ni = ni > 499 ? 499 : ni;
    dnmask |= (unsigned)(ni - f) << t; // in {0,1}
  }
  int f1 = (f + 1 > 499) ? 499 : f + 1;
  int f2 = (f + 2 > 499) ? 499 : f + 2;
  float s0 = sf0[f], s1 = sf0[f1], s2 = sf0[f2];

  float acc[16];
#pragma unroll
  for (int t = 0; t < 16; ++t) acc[t] = 0.0f;

  for (int pp = 0; pp < 16; ++pp) {
    int p = g * 16 + pp;
    float pf = (float)(p + 1);
    float fs0 = __fmul_rn(s0, pf);
    float fs1 = __fmul_rn(s1, pf);
    if (!(fs0 < 22050.0f) && !(fs1 < 22050.0f)) break;
    float fs2 = __fmul_rn(s2, pf);
    size_t pbase = ((size_t)(b * NPART + p)) * 5500;
    float left = (mm_ > 0) ? pref4[pbase + mm_ - 1] : 0.0f;
    float P4 = pref4[pbase + mm_];
    float v[16];
#pragma unroll
    for (int t = 0; t < 16; ++t) {
      bool d = (damask >> t) & 1;
      float fa = d ? fs1 : fs0;
      float fb = d ? fs2 : fs1;
      float fu = __fadd_rn(__fmul_rn(fa, wm[t]), __fmul_rn(fb, wv[t]));
      v[t] = div_sr(fu);
    }
    float s1t[8];
#pragma unroll
    for (int t = 0; t < 8; ++t) s1t[t] = __fadd_rn(v[2 * t], v[2 * t + 1]);
    float s2t[4];
#pragma unroll
    for (int t = 0; t < 4; ++t) s2t[t] = __fadd_rn(s1t[2 * t], s1t[2 * t + 1]);
    float s3_0 = __fadd_rn(s2t[0], s2t[1]);
    bool fz = (mm_ == 0);
    float l3_0 = fz ? s3_0 : __fadd_rn(left, s3_0);
    float l2_0 = fz ? s2t[0] : __fadd_rn(left, s2t[0]);
    float l2_1 = l3_0;
    float l2_2 = __fadd_rn(l3_0, s2t[2]);
    float l2_3 = P4;
    float l1_0 = fz ? s1t[0] : __fadd_rn(left, s1t[0]);
    float l1_1 = l2_0;
    float l1_2 = __fadd_rn(l2_0, s1t[2]);
    float l1_3 = l2_1;
    float l1_4 = __fadd_rn(l2_1, s1t[4]);
    float l1_5 = l2_2;
    float l1_6 = __fadd_rn(l2_2, s1t[6]);
    float l1_7 = l2_3;
    float ph[16];
    ph[0]  = fz ? v[0] : __fadd_rn(left, v[0]);
    ph[1]  = l1_0;
    ph[2]  = __fadd_rn(l1_0, v[2]);
    ph[3]  = l1_1;
    ph[4]  = __fadd_rn(l1_1, v[4]);
    ph[5]  = l1_2;
    ph[6]  = __fadd_rn(l1_2, v[6]);
    ph[7]  = l1_3;
    ph[8]  = __fadd_rn(l1_3, v[8]);
    ph[9]  = l1_4;
    ph[10] = __fadd_rn(l1_4, v[10]);
    ph[11] = l1_5;
    ph[12] = __fadd_rn(l1_5, v[12]);
    ph[13] = l1_6;
    ph[14] = __fadd_rn(l1_6, v[14]);
    ph[15] = l1_7;
    float ga0 = amp[((size_t)(b * NT + f)) * 64 + p];
    float ga1 = amp[((size_t)(b * NT + f1)) * 64 + p];
    float ga2 = amp[((size_t)(b * NT + f2)) * 64 + p];
#pragma unroll
    for (int t = 0; t < 16; ++t) {
      bool dn = (dnmask >> t) & 1;
      float fr = dn ? fs1 : fs0;
      if (fr < 22050.0f) {
        float x = __fmul_rn(ph[t], TWOPI_F);
        float s = sin_fast(x);
        bool d = (damask >> t) & 1;
        float lo = d ? ga1 : ga0;
        float hi = d ? ga2 : ga1;
        float au = __builtin_fmaf(__fsub_rn(hi, lo), wv[t], lo);
        acc[t] = __builtin_fmaf(s, au, acc[t]);
      }
    }
  }
  if (act) {
    size_t obase = ((size_t)g * NBATCH + b) * TAUD + (size_t)j0;
#pragma unroll
    for (int t = 0; t < 16; ++t) hpart[obase + t] = acc[t];
  }
}

// ---------------- circular convolution (truncated +-LCONV=256) ----------------
#define CT    1024
#define PSTR  392
__global__ __launch_bounds__(256) void k_conv(const float* __restrict__ noise,
                                              const float* __restrict__ hh,
                                              float* __restrict__ ynz) {
  int b = blockIdx.y;
  int t0 = blockIdx.x * CT;
  int tid = threadIdx.x;
  __shared__ float xsp[4 * PSTR];     // window x[t0-256 .. t0+CT+256)
  __shared__ float hsh[LCONV];        // h[1..256]
  const float* hb = hh + b * (LCONV + 1);
  for (int i = tid; i < CT + 2 * LCONV; i += 256) {
    int j = t0 - LCONV + i;
    if (j < 0) j += TAUD;
    else if (j >= TAUD) j -= TAUD;
    xsp[(i & 3) * PSTR + (i >> 2)] = noise[(size_t)b * TAUD + j];
  }
  hsh[tid] = hb[1 + tid];             // LCONV == blockDim == 256
  __syncthreads();
  float h0 = hb[0];
  int B4 = tid + 64;                  // plane row of x[t0 + 4*tid]
  float a0 = h0 * xsp[0 * PSTR + B4];
  float a1 = h0 * xsp[1 * PSTR + B4];
  float a2 = h0 * xsp[2 * PSTR + B4];
  float a3 = h0 * xsp[3 * PSTR + B4];
  for (int g = 0; g < 32; ++g) {      // taps d = 8g+1 .. 8g+8
    int km = tid + 62 - 2 * g;        // minus side base (plane k)
    int kp = tid + 64 + 2 * g;        // plus side base
    float mv0 = xsp[0 * PSTR + km],     mv1 = xsp[1 * PSTR + km];
    float mv2 = xsp[2 * PSTR + km],     mv3 = xsp[3 * PSTR + km];
    float mv4 = xsp[0 * PSTR + km + 1], mv5 = xsp[1 * PSTR + km + 1];
    float mv6 = xsp[2 * PSTR + km + 1], mv7 = xsp[3 * PSTR + km + 1];
    float mv8 = xsp[0 * PSTR + km + 2], mv9 = xsp[1 * PSTR + km + 2];
    float mv10 = xsp[2 * PSTR + km + 2];
    float pv1 = xsp[1 * PSTR + kp],     pv2 = xsp[2 * PSTR + kp];
    float pv3 = xsp[3 * PSTR + kp];
    float pv4 = xsp[0 * PSTR + kp + 1], pv5 = xsp[1 * PSTR + kp + 1];
    float pv6 = xsp[2 * PSTR + kp + 1], pv7 = xsp[3 * PSTR + kp + 1];
    float pv8 = xsp[0 * PSTR + kp + 2], pv9 = xsp[1 * PSTR + kp + 2];
    float pv10 = xsp[2 * PSTR + kp + 2], pv11 = xsp[3 * PSTR + kp + 2];
    int hbase = 8 * g;                // uniform -> broadcast reads
    float hv0 = hsh[hbase + 0], hv1 = hsh[hbase + 1];
    float hv2 = hsh[hbase + 2], hv3 = hsh[hbase + 3];
    float hv4 = hsh[hbase + 4], hv5 = hsh[hbase + 5];
    float hv6 = hsh[hbase + 6], hv7 = hsh[hbase + 7];
    a0 = fmaf(hv0, mv7 + pv1, a0);
    a0 = fmaf(hv1, mv6 + pv2, a0);
    a0 = fmaf(hv2, mv5 + pv3, a0);
    a0 = fmaf(hv3, mv4 + pv4, a0);
    a0 = fmaf(hv4, mv3 + pv5, a0);
    a0 = fmaf(hv5, mv2 + pv6, a0);
    a0 = fmaf(hv6, mv1 + pv7, a0);
    a0 = fmaf(hv7, mv0 + pv8, a0);
    a1 = fmaf(hv0, mv8 + pv2, a1);
    a1 = fmaf(hv1, mv7 + pv3, a1);
    a1 = fmaf(hv2, mv6 + pv4, a1);
    a1 = fmaf(hv3, mv5 + pv5, a1);
    a1 = fmaf(hv4, mv4 + pv6, a1);
    a1 = fmaf(hv5, mv3 + pv7, a1);
    a1 = fmaf(hv6, mv2 + pv8, a1);
    a1 = fmaf(hv7, mv1 + pv9, a1);
    a2 = fmaf(hv0, mv9 + pv3, a2);
    a2 = fmaf(hv1, mv8 + pv4, a2);
    a2 = fmaf(hv2, mv7 + pv5, a2);
    a2 = fmaf(hv3, mv6 + pv6, a2);
    a2 = fmaf(hv4, mv5 + pv7, a2);
    a2 = fmaf(hv5, mv4 + pv8, a2);
    a2 = fmaf(hv6, mv3 + pv9, a2);
    a2 = fmaf(hv7, mv2 + pv10, a2);
    a3 = fmaf(hv0, mv10 + pv4, a3);
    a3 = fmaf(hv1, mv9 + pv5, a3);
    a3 = fmaf(hv2, mv8 + pv6, a3);
    a3 = fmaf(hv3, mv7 + pv7, a3);
    a3 = fmaf(hv4, mv6 + pv8, a3);
    a3 = fmaf(hv5, mv5 + pv9, a3);
    a3 = fmaf(hv6, mv4 + pv10, a3);
    a3 = fmaf(hv7, mv3 + pv11, a3);
  }
  int t = t0 + tid * 4;
  if (t < TAUD) {                     // TAUD%4==0 -> all 4 valid together
    float4 o = make_float4(a0 * 0.1f, a1 * 0.1f, a2 * 0.1f, a3 * 0.1f);
    *reinterpret_cast<float4*>(&ynz[(size_t)b * TAUD + t]) = o;
  }
}

// ---------------- final mix ----------------
__global__ __launch_bounds__(256) void k_final(const float* __restrict__ hpart,
                                               const float* __restrict__ ynz,
                                               const float* __restrict__ loud,
                                               float* __restrict__ out) {
  int idx = blockIdx.x * 256 + threadIdx.x;
  if (idx >= NBATCH * TAUD) return;
  int b = idx / TAUD, j = idx - b * TAUD;
  int i0, i1; float w;
  iparams(j, i0, i1, w);
  float env = __fadd_rn(__fmul_rn(loud[b * NT + i0], __fsub_rn(1.0f, w)),
                        __fmul_rn(loud[b * NT + i1], w));
  const size_t S = (size_t)NBATCH * TAUD;
  float hsum = __fadd_rn(__fadd_rn(__fadd_rn(hpart[idx], hpart[S + idx]),
                                   hpart[2 * S + idx]),
                         hpart[3 * S + idx]);
  out[idx] = __fmul_rn(__fadd_rn(hsum, ynz[idx]), env);
}

}  // namespace

extern "C" void kernel_launch(void* const* d_in, const int* in_sizes, int n_in,
                              void* d_out, int out_size, void* d_ws, size_t ws_size,
                              hipStream_t stream) {
  const float* z    = (const float*)d_in[0];
  const float* f0n  = (const float*)d_in[1];
  const float* loud = (const float*)d_in[2];
  const float* nz   = (const float*)d_in[3];
  const float* W1p  = (const float*)d_in[4];
  const float* b1p  = (const float*)d_in[5];
  const float* W2p  = (const float*)d_in[6];
  const float* b2p  = (const float*)d_in[7];
  const float* W1n  = (const float*)d_in[8];
  const float* b1n  = (const float*)d_in[9];
  const float* W2n  = (const float*)d_in[10];
  const float* b2n  = (const float*)d_in[11];
  float* out = (float*)d_out;
  float* ws  = (float*)d_ws;

  size_t off = 0;
  float* amp   = ws + off; off += (size_t)NBATCH * NT * NPART;          // 256,000
  float* nmag  = ws + off; off += (size_t)NBATCH * NT * NBINS;          // 1,024,000
  float* f0hz  = ws + off; off += (size_t)NBATCH * NT;                  // 4,000
  float* mmw   = ws + off; off += (size_t)NBATCH * NBINS;               // 2,048
  float* G     = ws + off; off += (size_t)BSLC * (LCONV + 1) * NBINS;   // 526,336
  float* hh    = ws + off; off += (size_t)NBATCH * (LCONV + 1);         // 2,056
  float* ynz   = ws + off; off += (size_t)NBATCH * TAUD;                // 704,000
  float* lev4  = ws + off; off += (size_t)NBATCH * NPART * 5500;        // 2,816,000
  float* pref4 = ws + off; off += (size_t)NBATCH * NPART * 5500;        // 2,816,000
  float* hpart = ws + off; off += (size_t)4 * NBATCH * TAUD;            // 2,816,000
  (void)ws_size; (void)in_sizes; (void)n_in; (void)out_size;            // ~43.8 MB total

  // hp/hn alias hpart: consumed by k_mlp2 before k_harm overwrites hpart.
  float* hp = hpart;                      // 1,024,000 floats
  float* hn = hpart + (size_t)1024000;    // 1,024,000 floats (< 2,816,000)

  double HI = log2(2093.0), LO = log2(32.7);
  float C1 = (float)(HI - LO), C2 = (float)LO;

  dim3 gb(LCONV + 1, BSLC);
  k_basis<<<gb, 256, 0, stream>>>(G);
  k_f0<<<(NBATCH * NT + 255) / 256, 256, 0, stream>>>(f0n, f0hz, C1, C2);
  dim3 g1(4, 63);
  k_mlp1<<<g1, 256, 0, stream>>>(z, W1p, b1p, W1n, b1n, hp, hn);
  dim3 g2(5, 63);
  k_mlp2<<<g2, 256, 0, stream>>>(hp, hn, W2p, b2p, W2n, b2n, amp, nmag);
  k_mean<<<NBATCH, 256, 0, stream>>>(nmag, mmw);
  k_hc<<<LCONV + 1, 256, 0, stream>>>(mmw, G, hh);
  dim3 gl(22, NBATCH);
  k_lev4<<<gl, 256, 0, stream>>>(f0hz, lev4);
  k_scan_rest<<<NBATCH * NPART, 256, 0, stream>>>(lev4, pref4);
  dim3 gh(22, NBATCH, 4);
  k_harm<<<gh, 256, 0, stream>>>(f0hz, amp, pref4, hpart);
  dim3 gc((TAUD + CT - 1) / CT, NBATCH);
  k_conv<<<gc, 256, 0, stream>>>(nz, hh, ynz);
  k_final<<<(NBATCH * TAUD + 255) / 256, 256, 0, stream>>>(hpart, ynz, loud, out);
}

// Round 12
// 165.315 us; speedup vs baseline: 1.2748x; 1.1648x over previous
//
#include <hip/hip_runtime.h>
#include <cmath>

// DDSP decoder, bit-exact-phase implementation.
// R12: occupancy fixes + fusion. k_lev4 grid (22,8)->(22,8,4) (0.7->2.75
//      blocks/CU; per-(m,p) ops unchanged -> bit-identical). k_mean split
//      into 80-block partial + combine (reassoc ~1e-7, noise path only).
//      k_hc batch loop -> grid dim (bit-identical). k_final fused into
//      k_conv with identical op order (drops ynz round-trip + 1 launch).

#define NBATCH 8
#define NT     500
#define ND     128
#define TAUD   88000
#define NPART  64
#define NBINS  256
#define NFREQ  44001
#define LCONV  256
#define BSLC   8

namespace {

constexpr float  SCALE_TA = (float)(500.0 / 88000.0);   // lin_interp scale, fp32 like jnp
constexpr float  SCALE_NF = (float)(256.0 / 44001.0);
constexpr float  TWOPI_F  = (float)6.283185307179586476925286766559;
constexpr float  CANG     = (float)(6.283185307179586476925286766559 / 88000.0);
constexpr float  INV_SR   = 1.0f / 44100.0f;            // RN reciprocal
constexpr float  INV2PI_F = 0.15915494309189535f;       // RN(1/2pi)
constexpr float  PI2_HI   = 6.2831854820251464844f;     // RN(2pi) fp32
constexpr float  PI2_LO   = -1.7484556000744487e-7f;    // RN(2pi - PI2_HI)

__device__ __forceinline__ void iparams(int j, int& i0, int& i1, float& w) {
  float jf  = (float)j;
  float src = __fsub_rn(__fmul_rn(__fadd_rn(jf, 0.5f), SCALE_TA), 0.5f);
  src = fminf(fmaxf(src, 0.0f), 499.0f);
  int a = (int)src;            // floor (src >= 0)
  i0 = a;
  i1 = (a + 1 > 499) ? 499 : (a + 1);
  w  = __fsub_rn(src, (float)a);
}

// correctly-rounded x/44100 (Markstein: RN recip + 2 fma) == __fdiv_rn
__device__ __forceinline__ float div_sr(float x) {
  float q0 = __fmul_rn(x, INV_SR);
  float e  = __builtin_fmaf(-44100.0f, q0, x);
  return __builtin_fmaf(e, INV_SR, q0);
}

// sin of the fp32 value x (|x| up to ~3e5): float Cody-Waite reduce + v_sin.
__device__ __forceinline__ float sin_fast(float x) {
  float k = rintf(__fmul_rn(x, INV2PI_F));
  float r = __builtin_fmaf(-k, PI2_HI, x);
  r = __builtin_fmaf(-k, PI2_LO, r);
  return __sinf(r);
}

// ---------------- f0 (Hz) ----------------
__global__ __launch_bounds__(256) void k_f0(const float* __restrict__ f0n,
                                            float* __restrict__ f0hz,
                                            float C1, float C2) {
  int i = blockIdx.x * 256 + threadIdx.x;
  if (i < NBATCH * NT) {
    float x = __fadd_rn(__fmul_rn(f0n[i], C1), C2);
    f0hz[i] = (float)exp2((double)x);
  }
}

// ---------------- MLP layer 1: hp/hn = relu(z @ W1{p,n} + b) ----------------
__global__ __launch_bounds__(256) void k_mlp1(
    const float* __restrict__ z,
    const float* __restrict__ W1p, const float* __restrict__ b1p,
    const float* __restrict__ W1n, const float* __restrict__ b1n,
    float* __restrict__ hp, float* __restrict__ hn) {
  int ct = blockIdx.x;               // col tile 0..3
  int rt = blockIdx.y;               // row tile 0..62
  int tid = threadIdx.x;
  int tx = tid & 15, ty = tid >> 4;
  int col0 = ct * 64 + tx * 4;
  int row0 = rt * 64 + ty * 4;
  __shared__ float zs[64][129];      // padded: conflict-free column reads
  for (int i = tid; i < 64 * 32; i += 256) {
    int r = i >> 5, q = (i & 31) * 4;
    int gr = rt * 64 + r; if (gr > 3999) gr = 3999;
    float4 v = *(const float4*)&z[(size_t)gr * ND + q];
    zs[r][q] = v.x; zs[r][q + 1] = v.y; zs[r][q + 2] = v.z; zs[r][q + 3] = v.w;
  }
  __syncthreads();
  float accp[4][4], accn[4][4];
#pragma unroll
  for (int c = 0; c < 4; ++c) {
    float bp = b1p[col0 + c], bn = b1n[col0 + c];
#pragma unroll
    for (int r = 0; r < 4; ++r) { accp[r][c] = bp; accn[r][c] = bn; }
  }
#pragma unroll 2
  for (int d = 0; d < ND; ++d) {
    float4 wp = *(const float4*)&W1p[d * 256 + col0];
    float4 wn = *(const float4*)&W1n[d * 256 + col0];
    float zv[4];
#pragma unroll
    for (int r = 0; r < 4; ++r) zv[r] = zs[ty * 4 + r][d];
#pragma unroll
    for (int r = 0; r < 4; ++r) {
      accp[r][0] = fmaf(zv[r], wp.x, accp[r][0]);
      accp[r][1] = fmaf(zv[r], wp.y, accp[r][1]);
      accp[r][2] = fmaf(zv[r], wp.z, accp[r][2]);
      accp[r][3] = fmaf(zv[r], wp.w, accp[r][3]);
      accn[r][0] = fmaf(zv[r], wn.x, accn[r][0]);
      accn[r][1] = fmaf(zv[r], wn.y, accn[r][1]);
      accn[r][2] = fmaf(zv[r], wn.z, accn[r][2]);
      accn[r][3] = fmaf(zv[r], wn.w, accn[r][3]);
    }
  }
#pragma unroll
  for (int r = 0; r < 4; ++r) {
    int gr = row0 + r;
    if (gr < 4000) {
      float4 op = make_float4(fmaxf(accp[r][0], 0.0f), fmaxf(accp[r][1], 0.0f),
                              fmaxf(accp[r][2], 0.0f), fmaxf(accp[r][3], 0.0f));
      float4 on = make_float4(fmaxf(accn[r][0], 0.0f), fmaxf(accn[r][1], 0.0f),
                              fmaxf(accn[r][2], 0.0f), fmaxf(accn[r][3], 0.0f));
      *(float4*)&hp[(size_t)gr * 256 + col0] = op;
      *(float4*)&hn[(size_t)gr * 256 + col0] = on;
    }
  }
}

// ---------------- MLP layer 2: nmag = sigmoid(hn@W2n+b), amp = sigmoid(hp@W2p+b) ----
__global__ __launch_bounds__(256) void k_mlp2(
    const float* __restrict__ hp, const float* __restrict__ hn,
    const float* __restrict__ W2p, const float* __restrict__ b2p,
    const float* __restrict__ W2n, const float* __restrict__ b2n,
    float* __restrict__ amp, float* __restrict__ nmag) {
  int ct = blockIdx.x;               // 0..4
  int rt = blockIdx.y;               // 0..62
  int tid = threadIdx.x;
  int tx = tid & 15, ty = tid >> 4;
  bool isAmp = (ct == 4);
  const float* hsrc = isAmp ? hp : hn;
  const float* Wsrc = isAmp ? W2p : W2n;
  const float* bias = isAmp ? b2p : b2n;
  int ncols = isAmp ? 64 : 256;
  int col0 = isAmp ? tx * 4 : ct * 64 + tx * 4;
  int row0 = rt * 64 + ty * 4;
  __shared__ float hs[64][129];
  float acc[4][4];
#pragma unroll
  for (int c = 0; c < 4; ++c) {
    float bv = bias[col0 + c];
#pragma unroll
    for (int r = 0; r < 4; ++r) acc[r][c] = bv;
  }
  for (int kc = 0; kc < 2; ++kc) {
    for (int i = tid; i < 64 * 32; i += 256) {
      int r = i >> 5, q = (i & 31) * 4;
      int gr = rt * 64 + r; if (gr > 3999) gr = 3999;
      float4 v = *(const float4*)&hsrc[(size_t)gr * 256 + kc * 128 + q];
      hs[r][q] = v.x; hs[r][q + 1] = v.y; hs[r][q + 2] = v.z; hs[r][q + 3] = v.w;
    }
    __syncthreads();
#pragma unroll 4
    for (int d = 0; d < 128; ++d) {
      float4 w = *(const float4*)&Wsrc[(size_t)(kc * 128 + d) * ncols + col0];
      float hv[4];
#pragma unroll
      for (int r = 0; r < 4; ++r) hv[r] = hs[ty * 4 + r][d];
#pragma unroll
      for (int r = 0; r < 4; ++r) {
        acc[r][0] = fmaf(hv[r], w.x, acc[r][0]);
        acc[r][1] = fmaf(hv[r], w.y, acc[r][1]);
        acc[r][2] = fmaf(hv[r], w.z, acc[r][2]);
        acc[r][3] = fmaf(hv[r], w.w, acc[r][3]);
      }
    }
    __syncthreads();
  }
#pragma unroll
  for (int r = 0; r < 4; ++r) {
    int gr = row0 + r;
    if (gr < 4000) {
      float4 o = make_float4(1.0f / (1.0f + expf(-acc[r][0])),
                             1.0f / (1.0f + expf(-acc[r][1])),
                             1.0f / (1.0f + expf(-acc[r][2])),
                             1.0f / (1.0f + expf(-acc[r][3])));
      if (isAmp) *(float4*)&amp[(size_t)gr * 64 + col0] = o;
      else       *(float4*)&nmag[(size_t)gr * 256 + col0] = o;
    }
  }
}

// ---------------- mean over frames, two-stage (reassoc ~1e-7, noise path) --------
__global__ __launch_bounds__(256) void k_mean1(const float* __restrict__ nmag,
                                               float* __restrict__ mmpart) {
  int b = blockIdx.x, seg = blockIdx.y;     // 10 segments of 50 frames
  int k = threadIdx.x;
  float s = 0.0f;
  int t0 = seg * 50;
  for (int t = t0; t < t0 + 50; ++t) s += nmag[((size_t)b * NT + t) * 256 + k];
  mmpart[((size_t)b * 10 + seg) * 256 + k] = s;
}

__global__ __launch_bounds__(256) void k_mean2(const float* __restrict__ mmpart,
                                               float* __restrict__ mm) {
  int b = blockIdx.x;
  int k = threadIdx.x;
  float s = 0.0f;
  for (int seg = 0; seg < 10; ++seg) s += mmpart[((size_t)b * 10 + seg) * 256 + k];
  mm[b * 256 + k] = s * (1.0f / 500.0f);
}

// ---------------- basis G[s][n][i] = partial_s sum_k hat_i(k) cos(2 pi n k/88000) ----
__global__ __launch_bounds__(256) void k_basis(float* __restrict__ G) {
  int n = blockIdx.x;       // 0..LCONV
  int s = blockIdx.y;       // slice 0..BSLC-1
  int i = threadIdx.x;      // bin 0..255
  int start = 1, end = 43999;
  if (i > 0) {
    int s0 = (int)(((float)i - 0.5f) * 171.87890625f - 0.5f) - 4;
    if (s0 > start) start = s0;
  }
  int e0 = (int)(((float)i + 1.5f) * 171.87890625f - 0.5f) + 4;
  if (e0 < end) end = e0;
  int len = (end - start + BSLC) / BSLC;      // ceil
  int ks = start + s * len;
  int ke = ks + len - 1; if (ke > end) ke = end;
  float acc = 0.0f;
  if (ks <= ke) {
    int m = (int)(((long long)n * ks) % TAUD);
    for (int k = ks; k <= ke; ++k) {
      float kf  = (float)k;
      float src = __fsub_rn(__fmul_rn(__fadd_rn(kf, 0.5f), SCALE_NF), 0.5f);
      src = fminf(fmaxf(src, 0.0f), 255.0f);
      int i0 = (int)src;
      float w = __fsub_rn(src, (float)i0);
      float wt = 0.0f;
      if (i0 == i) wt = __fsub_rn(1.0f, w);
      int i1 = (i0 < 255) ? i0 + 1 : 255;
      if (i1 == i) wt = __fadd_rn(wt, w);
      acc = fmaf(wt, __cosf((float)m * CANG), acc);
      m += n; if (m >= TAUD) m -= TAUD;
    }
  }
  G[((size_t)s * (LCONV + 1) + n) * 256 + i] = acc;
}

// ---------------- combine: h[b][n] = (F0 +- FN + 2*sum_i mm_i G[n][i]) / N ----------------
__global__ __launch_bounds__(256) void k_hc(const float* __restrict__ mm,
                                            const float* __restrict__ G,
                                            float* __restrict__ hh) {
  int n = blockIdx.x;       // 0..LCONV
  int b = blockIdx.y;       // batch
  int tid = threadIdx.x;
  const size_t GS = (size_t)(LCONV + 1) * 256;
  size_t gi = (size_t)n * 256 + tid;
  float g01 = G[gi] + G[GS + gi];
  float g23 = G[2 * GS + gi] + G[3 * GS + gi];
  float g45 = G[4 * GS + gi] + G[5 * GS + gi];
  float g67 = G[6 * GS + gi] + G[7 * GS + gi];
  float g = (g01 + g23) + (g45 + g67);
  __shared__ float red[256];
  red[tid] = mm[b * 256 + tid] * g;
  __syncthreads();
  for (int st = 128; st > 0; st >>= 1) {
    if (tid < st) red[tid] += red[tid + st];
    __syncthreads();
  }
  if (tid == 0) {
    float F0 = mm[b * 256 + 0];
    float src = __fsub_rn(__fmul_rn(__fadd_rn(44000.0f, 0.5f), SCALE_NF), 0.5f);
    src = fminf(fmaxf(src, 0.0f), 255.0f);
    int i0 = (int)src;
    float w = __fsub_rn(src, (float)i0);
    int i1 = (i0 < 255) ? i0 + 1 : 255;
    float FN = __fadd_rn(__fmul_rn(mm[b * 256 + i0], __fsub_rn(1.0f, w)),
                         __fmul_rn(mm[b * 256 + i1], w));
    float tot = 2.0f * red[0] + F0 + ((n & 1) ? -FN : FN);
    hh[b * (LCONV + 1) + n] = tot * (1.0f / 88000.0f);
  }
}

// ---------------- level-4 block sums (preamble amortized over 16 partials) ----------
__global__ __launch_bounds__(256) void k_lev4(const float* __restrict__ f0hz,
                                              float* __restrict__ lev4) {
  int chunk = blockIdx.x, b = blockIdx.y, g = blockIdx.z;
  int tid = threadIdx.x;
  int m = chunk * 256 + tid;
  bool act = (m < 5500);
  __shared__ float sf0[NT];
  for (int i = tid; i < NT; i += 256) sf0[i] = f0hz[b * NT + i];
  __syncthreads();
  if (!act) return;
  int j0 = m * 16;
  float wv[16], wm[16];
  unsigned damask = 0;
  int f = 0;
#pragma unroll
  for (int t = 0; t < 16; ++t) {
    int j = j0 + t;
    float jf = (float)j;
    float src = __fsub_rn(__fmul_rn(__fadd_rn(jf, 0.5f), SCALE_TA), 0.5f);
    src = fminf(fmaxf(src, 0.0f), 499.0f);
    int a = (int)src;
    if (t == 0) f = a;
    wv[t] = __fsub_rn(src, (float)a);
    wm[t] = __fsub_rn(1.0f, wv[t]);
    damask |= (unsigned)(a - f) << t;
  }
  int f1 = (f + 1 > 499) ? 499 : f + 1;
  int f2 = (f + 2 > 499) ? 499 : f + 2;
  float s0 = sf0[f], s1 = sf0[f1], s2 = sf0[f2];
  for (int pp = 0; pp < 16; ++pp) {
    int p = g * 16 + pp;
    float pf = (float)(p + 1);
    float fs0 = __fmul_rn(s0, pf);
    float fs1 = __fmul_rn(s1, pf);
    float fs2 = __fmul_rn(s2, pf);
    float v[16];
#pragma unroll
    for (int t = 0; t < 16; ++t) {
      bool d = (damask >> t) & 1;
      float fa = d ? fs1 : fs0;
      float fb = d ? fs2 : fs1;
      float fu = __fadd_rn(__fmul_rn(fa, wm[t]), __fmul_rn(fb, wv[t]));
      v[t] = div_sr(fu);
    }
    float s1t[8];
#pragma unroll
    for (int t = 0; t < 8; ++t) s1t[t] = __fadd_rn(v[2 * t], v[2 * t + 1]);
    float s2t[4];
#pragma unroll
    for (int t = 0; t < 4; ++t) s2t[t] = __fadd_rn(s1t[2 * t], s1t[2 * t + 1]);
    float s3a = __fadd_rn(s2t[0], s2t[1]);
    float s3b = __fadd_rn(s2t[2], s2t[3]);
    lev4[((size_t)(b * NPART + p)) * 5500 + m] = __fadd_rn(s3a, s3b);
  }
}

// ---------------- scan upper levels: Brent-Kung on loaded lev4 ----------------
__global__ __launch_bounds__(256) void k_scan_rest(const float* __restrict__ lev4,
                                                   float* __restrict__ pref4) {
  int bp = blockIdx.x;
  __shared__ float lev[10992];
  int tid = threadIdx.x;
  for (int m = tid; m < 5500; m += 256) lev[m] = lev4[(size_t)bp * 5500 + m];
  __syncthreads();
  const int sizes[13] = {5500, 2750, 1375, 687, 343, 171, 85, 42, 21, 10, 5, 2, 1};
  const int offs[13]  = {0, 5500, 8250, 9625, 10312, 10655, 10826, 10911,
                         10953, 10974, 10984, 10989, 10991};
  for (int L = 1; L < 13; ++L) {
    int n = sizes[L];
    const float* src = lev + offs[L - 1];
    float* dst = lev + offs[L];
    for (int k2 = tid; k2 < n; k2 += 256)
      dst[k2] = __fadd_rn(src[2 * k2], src[2 * k2 + 1]);
    __syncthreads();
  }
  for (int L = 11; L >= 0; --L) {
    int n = sizes[L];
    float* cur = lev + offs[L];
    const float* up = lev + offs[L + 1];
    for (int idx = 1 + tid; idx < n; idx += 256) {
      float val;
      if (idx & 1) val = up[(idx - 1) >> 1];
      else         val = __fadd_rn(up[(idx >> 1) - 1], cur[idx]);
      cur[idx] = val;
    }
    __syncthreads();
  }
  for (int m = tid; m < 5500; m += 256)
    pref4[(size_t)bp * 5500 + m] = lev[m];
}

// ---------------- fused harmonic synth ----------------
__global__ __launch_bounds__(256) void k_harm(const float* __restrict__ f0hz,
                                              const float* __restrict__ amp,
                                              const float* __restrict__ pref4,
                                              float* __restrict__ hpart) {
  int chunk = blockIdx.x, b = blockIdx.y, g = blockIdx.z;
  int tid = threadIdx.x;
  int m = chunk * 256 + tid;
  bool act = (m < 5500);
  __shared__ float sf0[NT];
  for (int i = tid; i < NT; i += 256) sf0[i] = f0hz[b * NT + i];
  __syncthreads();
  int mm_ = act ? m : 0;
  int j0 = mm_ * 16;
  float wv[16], wm[16];
  unsigned damask = 0, dnmask = 0;
  int f = 0;
#pragma unroll
  for (int t = 0; t < 16; ++t) {
    int j = j0 + t;
    float jf = (float)j;
    float src = __fsub_rn(__fmul_rn(__fadd_rn(jf, 0.5f), SCALE_TA), 0.5f);
    src = fminf(fmaxf(src, 0.0f), 499.0f);
    int a = (int)src;
    if (t == 0) f = a;                 // i0 monotone nondecreasing in j
    wv[t] = __fsub_rn(src, (float)a);
    wm[t] = __fsub_rn(1.0f, wv[t]);
    damask |= (unsigned)(a - f) << t;  // in {0,1}
    int ni = (int)__fmul_rn(jf, SCALE_TA);
    ni = ni > 499 ? 499 : ni;
    dnmask |= (unsigned)(ni - f) << t; // in {0,1}
  }
  int f1 = (f + 1 > 499) ? 499 : f + 1;
  int f2 = (f + 2 > 499) ? 499 : f + 2;
  float s0 = sf0[f], s1 = sf0[f1], s2 = sf0[f2];

  float acc[16];
#pragma unroll
  for (int t = 0; t < 16; ++t) acc[t] = 0.0f;

  for (int pp = 0; pp < 16; ++pp) {
    int p = g * 16 + pp;
    float pf = (float)(p + 1);
    float fs0 = __fmul_rn(s0, pf);
    float fs1 = __fmul_rn(s1, pf);
    if (!(fs0 < 22050.0f) && !(fs1 < 22050.0f)) break;
    float fs2 = __fmul_rn(s2, pf);
    size_t pbase = ((size_t)(b * NPART + p)) * 5500;
    float left = (mm_ > 0) ? pref4[pbase + mm_ - 1] : 0.0f;
    float P4 = pref4[pbase + mm_];
    float v[16];
#pragma unroll
    for (int t = 0; t < 16; ++t) {
      bool d = (damask >> t) & 1;
      float fa = d ? fs1 : fs0;
      float fb = d ? fs2 : fs1;
      float fu = __fadd_rn(__fmul_rn(fa, wm[t]), __fmul_rn(fb, wv[t]));
      v[t] = div_sr(fu);
    }
    float s1t[8];
#pragma unroll
    for (int t = 0; t < 8; ++t) s1t[t] = __fadd_rn(v[2 * t], v[2 * t + 1]);
    float s2t[4];
#pragma unroll
    for (int t = 0; t < 4; ++t) s2t[t] = __fadd_rn(s1t[2 * t], s1t[2 * t + 1]);
    float s3_0 = __fadd_rn(s2t[0], s2t[1]);
    bool fz = (mm_ == 0);
    float l3_0 = fz ? s3_0 : __fadd_rn(left, s3_0);
    float l2_0 = fz ? s2t[0] : __fadd_rn(left, s2t[0]);
    float l2_1 = l3_0;
    float l2_2 = __fadd_rn(l3_0, s2t[2]);
    float l2_3 = P4;
    float l1_0 = fz ? s1t[0] : __fadd_rn(left, s1t[0]);
    float l1_1 = l2_0;
    float l1_2 = __fadd_rn(l2_0, s1t[2]);
    float l1_3 = l2_1;
    float l1_4 = __fadd_rn(l2_1, s1t[4]);
    float l1_5 = l2_2;
    float l1_6 = __fadd_rn(l2_2, s1t[6]);
    float l1_7 = l2_3;
    float ph[16];
    ph[0]  = fz ? v[0] : __fadd_rn(left, v[0]);
    ph[1]  = l1_0;
    ph[2]  = __fadd_rn(l1_0, v[2]);
    ph[3]  = l1_1;
    ph[4]  = __fadd_rn(l1_1, v[4]);
    ph[5]  = l1_2;
    ph[6]  = __fadd_rn(l1_2, v[6]);
    ph[7]  = l1_3;
    ph[8]  = __fadd_rn(l1_3, v[8]);
    ph[9]  = l1_4;
    ph[10] = __fadd_rn(l1_4, v[10]);
    ph[11] = l1_5;
    ph[12] = __fadd_rn(l1_5, v[12]);
    ph[13] = l1_6;
    ph[14] = __fadd_rn(l1_6, v[14]);
    ph[15] = l1_7;
    float ga0 = amp[((size_t)(b * NT + f)) * 64 + p];
    float ga1 = amp[((size_t)(b * NT + f1)) * 64 + p];
    float ga2 = amp[((size_t)(b * NT + f2)) * 64 + p];
#pragma unroll
    for (int t = 0; t < 16; ++t) {
      bool dn = (dnmask >> t) & 1;
      float fr = dn ? fs1 : fs0;
      if (fr < 22050.0f) {
        float x = __fmul_rn(ph[t], TWOPI_F);
        float s = sin_fast(x);
        bool d = (damask >> t) & 1;
        float lo = d ? ga1 : ga0;
        float hi = d ? ga2 : ga1;
        float au = __builtin_fmaf(__fsub_rn(hi, lo), wv[t], lo);
        acc[t] = __builtin_fmaf(s, au, acc[t]);
      }
    }
  }
  if (act) {
    size_t obase = ((size_t)g * NBATCH + b) * TAUD + (size_t)j0;
#pragma unroll
    for (int t = 0; t < 16; ++t) hpart[obase + t] = acc[t];
  }
}

// ---------------- circular convolution + final mix (fused) ----------------
// Conv chain identical to R11's k_conv; epilogue applies k_final's exact op
// order: hsum = ((h0+h1)+h2)+h3; out = (hsum + a*0.1f) * env.
#define CT    1024
#define PSTR  392
__global__ __launch_bounds__(256) void k_convfinal(const float* __restrict__ noise,
                                                   const float* __restrict__ hh,
                                                   const float* __restrict__ hpart,
                                                   const float* __restrict__ loud,
                                                   float* __restrict__ out) {
  int b = blockIdx.y;
  int t0 = blockIdx.x * CT;
  int tid = threadIdx.x;
  __shared__ float xsp[4 * PSTR];     // window x[t0-256 .. t0+CT+256)
  __shared__ float hsh[LCONV];        // h[1..256]
  const float* hb = hh + b * (LCONV + 1);
  for (int i = tid; i < CT + 2 * LCONV; i += 256) {
    int j = t0 - LCONV + i;
    if (j < 0) j += TAUD;
    else if (j >= TAUD) j -= TAUD;
    xsp[(i & 3) * PSTR + (i >> 2)] = noise[(size_t)b * TAUD + j];
  }
  hsh[tid] = hb[1 + tid];             // LCONV == blockDim == 256
  __syncthreads();
  float h0 = hb[0];
  int B4 = tid + 64;                  // plane row of x[t0 + 4*tid]
  float a0 = h0 * xsp[0 * PSTR + B4];
  float a1 = h0 * xsp[1 * PSTR + B4];
  float a2 = h0 * xsp[2 * PSTR + B4];
  float a3 = h0 * xsp[3 * PSTR + B4];
  for (int g = 0; g < 32; ++g) {      // taps d = 8g+1 .. 8g+8
    int km = tid + 62 - 2 * g;        // minus side base (plane k)
    int kp = tid + 64 + 2 * g;        // plus side base
    float mv0 = xsp[0 * PSTR + km],     mv1 = xsp[1 * PSTR + km];
    float mv2 = xsp[2 * PSTR + km],     mv3 = xsp[3 * PSTR + km];
    float mv4 = xsp[0 * PSTR + km + 1], mv5 = xsp[1 * PSTR + km + 1];
    float mv6 = xsp[2 * PSTR + km + 1], mv7 = xsp[3 * PSTR + km + 1];
    float mv8 = xsp[0 * PSTR + km + 2], mv9 = xsp[1 * PSTR + km + 2];
    float mv10 = xsp[2 * PSTR + km + 2];
    float pv1 = xsp[1 * PSTR + kp],     pv2 = xsp[2 * PSTR + kp];
    float pv3 = xsp[3 * PSTR + kp];
    float pv4 = xsp[0 * PSTR + kp + 1], pv5 = xsp[1 * PSTR + kp + 1];
    float pv6 = xsp[2 * PSTR + kp + 1], pv7 = xsp[3 * PSTR + kp + 1];
    float pv8 = xsp[0 * PSTR + kp + 2], pv9 = xsp[1 * PSTR + kp + 2];
    float pv10 = xsp[2 * PSTR + kp + 2], pv11 = xsp[3 * PSTR + kp + 2];
    int hbase = 8 * g;                // uniform -> broadcast reads
    float hv0 = hsh[hbase + 0], hv1 = hsh[hbase + 1];
    float hv2 = hsh[hbase + 2], hv3 = hsh[hbase + 3];
    float hv4 = hsh[hbase + 4], hv5 = hsh[hbase + 5];
    float hv6 = hsh[hbase + 6], hv7 = hsh[hbase + 7];
    a0 = fmaf(hv0, mv7 + pv1, a0);
    a0 = fmaf(hv1, mv6 + pv2, a0);
    a0 = fmaf(hv2, mv5 + pv3, a0);
    a0 = fmaf(hv3, mv4 + pv4, a0);
    a0 = fmaf(hv4, mv3 + pv5, a0);
    a0 = fmaf(hv5, mv2 + pv6, a0);
    a0 = fmaf(hv6, mv1 + pv7, a0);
    a0 = fmaf(hv7, mv0 + pv8, a0);
    a1 = fmaf(hv0, mv8 + pv2, a1);
    a1 = fmaf(hv1, mv7 + pv3, a1);
    a1 = fmaf(hv2, mv6 + pv4, a1);
    a1 = fmaf(hv3, mv5 + pv5, a1);
    a1 = fmaf(hv4, mv4 + pv6, a1);
    a1 = fmaf(hv5, mv3 + pv7, a1);
    a1 = fmaf(hv6, mv2 + pv8, a1);
    a1 = fmaf(hv7, mv1 + pv9, a1);
    a2 = fmaf(hv0, mv9 + pv3, a2);
    a2 = fmaf(hv1, mv8 + pv4, a2);
    a2 = fmaf(hv2, mv7 + pv5, a2);
    a2 = fmaf(hv3, mv6 + pv6, a2);
    a2 = fmaf(hv4, mv5 + pv7, a2);
    a2 = fmaf(hv5, mv4 + pv8, a2);
    a2 = fmaf(hv6, mv3 + pv9, a2);
    a2 = fmaf(hv7, mv2 + pv10, a2);
    a3 = fmaf(hv0, mv10 + pv4, a3);
    a3 = fmaf(hv1, mv9 + pv5, a3);
    a3 = fmaf(hv2, mv8 + pv6, a3);
    a3 = fmaf(hv3, mv7 + pv7, a3);
    a3 = fmaf(hv4, mv6 + pv8, a3);
    a3 = fmaf(hv5, mv5 + pv9, a3);
    a3 = fmaf(hv6, mv4 + pv10, a3);
    a3 = fmaf(hv7, mv3 + pv11, a3);
  }
  int t = t0 + tid * 4;
  if (t < TAUD) {                     // TAUD%4==0 -> all 4 valid together
    const size_t S = (size_t)NBATCH * TAUD;
    size_t base = (size_t)b * TAUD + t;
    float4 h0v = *(const float4*)&hpart[base];
    float4 h1v = *(const float4*)&hpart[S + base];
    float4 h2v = *(const float4*)&hpart[2 * S + base];
    float4 h3v = *(const float4*)&hpart[3 * S + base];
    float yn[4] = {a0 * 0.1f, a1 * 0.1f, a2 * 0.1f, a3 * 0.1f};
    float hs0[4] = {h0v.x, h0v.y, h0v.z, h0v.w};
    float hs1[4] = {h1v.x, h1v.y, h1v.z, h1v.w};
    float hs2[4] = {h2v.x, h2v.y, h2v.z, h2v.w};
    float hs3[4] = {h3v.x, h3v.y, h3v.z, h3v.w};
    float o[4];
#pragma unroll
    for (int u = 0; u < 4; ++u) {
      int j = t + u;
      int i0, i1; float w;
      iparams(j, i0, i1, w);
      float env = __fadd_rn(__fmul_rn(loud[b * NT + i0], __fsub_rn(1.0f, w)),
                            __fmul_rn(loud[b * NT + i1], w));
      float hsum = __fadd_rn(__fadd_rn(__fadd_rn(hs0[u], hs1[u]), hs2[u]), hs3[u]);
      o[u] = __fmul_rn(__fadd_rn(hsum, yn[u]), env);
    }
    *reinterpret_cast<float4*>(&out[base]) = make_float4(o[0], o[1], o[2], o[3]);
  }
}

}  // namespace

extern "C" void kernel_launch(void* const* d_in, const int* in_sizes, int n_in,
                              void* d_out, int out_size, void* d_ws, size_t ws_size,
                              hipStream_t stream) {
  const float* z    = (const float*)d_in[0];
  const float* f0n  = (const float*)d_in[1];
  const float* loud = (const float*)d_in[2];
  const float* nz   = (const float*)d_in[3];
  const float* W1p  = (const float*)d_in[4];
  const float* b1p  = (const float*)d_in[5];
  const float* W2p  = (const float*)d_in[6];
  const float* b2p  = (const float*)d_in[7];
  const float* W1n  = (const float*)d_in[8];
  const float* b1n  = (const float*)d_in[9];
  const float* W2n  = (const float*)d_in[10];
  const float* b2n  = (const float*)d_in[11];
  float* out = (float*)d_out;
  float* ws  = (float*)d_ws;

  size_t off = 0;
  float* amp    = ws + off; off += (size_t)NBATCH * NT * NPART;          // 256,000
  float* nmag   = ws + off; off += (size_t)NBATCH * NT * NBINS;          // 1,024,000
  float* f0hz   = ws + off; off += (size_t)NBATCH * NT;                  // 4,000
  float* mmw    = ws + off; off += (size_t)NBATCH * NBINS;               // 2,048
  float* mmpart = ws + off; off += (size_t)NBATCH * 10 * NBINS;          // 20,480
  float* G      = ws + off; off += (size_t)BSLC * (LCONV + 1) * NBINS;   // 526,336
  float* hh     = ws + off; off += (size_t)NBATCH * (LCONV + 1);         // 2,056
  float* lev4   = ws + off; off += (size_t)NBATCH * NPART * 5500;        // 2,816,000
  float* pref4  = ws + off; off += (size_t)NBATCH * NPART * 5500;        // 2,816,000
  float* hpart  = ws + off; off += (size_t)4 * NBATCH * TAUD;            // 2,816,000
  (void)ws_size; (void)in_sizes; (void)n_in; (void)out_size;             // ~41 MB total

  // hp/hn alias hpart: consumed by k_mlp2 before k_harm overwrites hpart.
  float* hp = hpart;                      // 1,024,000 floats
  float* hn = hpart + (size_t)1024000;    // 1,024,000 floats (< 2,816,000)

  double HI = log2(2093.0), LO = log2(32.7);
  float C1 = (float)(HI - LO), C2 = (float)LO;

  dim3 gb(LCONV + 1, BSLC);
  k_basis<<<gb, 256, 0, stream>>>(G);
  k_f0<<<(NBATCH * NT + 255) / 256, 256, 0, stream>>>(f0n, f0hz, C1, C2);
  dim3 g1(4, 63);
  k_mlp1<<<g1, 256, 0, stream>>>(z, W1p, b1p, W1n, b1n, hp, hn);
  dim3 g2(5, 63);
  k_mlp2<<<g2, 256, 0, stream>>>(hp, hn, W2p, b2p, W2n, b2n, amp, nmag);
  dim3 gm(NBATCH, 10);
  k_mean1<<<gm, 256, 0, stream>>>(nmag, mmpart);
  k_mean2<<<NBATCH, 256, 0, stream>>>(mmpart, mmw);
  dim3 ghc(LCONV + 1, NBATCH);
  k_hc<<<ghc, 256, 0, stream>>>(mmw, G, hh);
  dim3 gl(22, NBATCH, 4);
  k_lev4<<<gl, 256, 0, stream>>>(f0hz, lev4);
  k_scan_rest<<<NBATCH * NPART, 256, 0, stream>>>(lev4, pref4);
  dim3 gh(22, NBATCH, 4);
  k_harm<<<gh, 256, 0, stream>>>(f0hz, amp, pref4, hpart);
  dim3 gc((TAUD + CT - 1) / CT, NBATCH);
  k_convfinal<<<gc, 256, 0, stream>>>(nz, hh, hpart, loud, out);
}

// Round 13
// 162.345 us; speedup vs baseline: 1.2981x; 1.0183x over previous
//
#include <hip/hip_runtime.h>
#include <cmath>

// DDSP decoder, bit-exact-phase implementation.
// R13: launch-count reduction (11 -> 9 kernels), all value-identical:
//      k_f0 inlined into k_lev4/k_harm staging (same exp2 chain per elem);
//      k_mean2 folded into k_hc (same ascending sum into LDS).

#define NBATCH 8
#define NT     500
#define ND     128
#define TAUD   88000
#define NPART  64
#define NBINS  256
#define NFREQ  44001
#define LCONV  256
#define BSLC   8

namespace {

constexpr float  SCALE_TA = (float)(500.0 / 88000.0);   // lin_interp scale, fp32 like jnp
constexpr float  SCALE_NF = (float)(256.0 / 44001.0);
constexpr float  TWOPI_F  = (float)6.283185307179586476925286766559;
constexpr float  CANG     = (float)(6.283185307179586476925286766559 / 88000.0);
constexpr float  INV_SR   = 1.0f / 44100.0f;            // RN reciprocal
constexpr float  INV2PI_F = 0.15915494309189535f;       // RN(1/2pi)
constexpr float  PI2_HI   = 6.2831854820251464844f;     // RN(2pi) fp32
constexpr float  PI2_LO   = -1.7484556000744487e-7f;    // RN(2pi - PI2_HI)

__device__ __forceinline__ void iparams(int j, int& i0, int& i1, float& w) {
  float jf  = (float)j;
  float src = __fsub_rn(__fmul_rn(__fadd_rn(jf, 0.5f), SCALE_TA), 0.5f);
  src = fminf(fmaxf(src, 0.0f), 499.0f);
  int a = (int)src;            // floor (src >= 0)
  i0 = a;
  i1 = (a + 1 > 499) ? 499 : (a + 1);
  w  = __fsub_rn(src, (float)a);
}

// correctly-rounded x/44100 (Markstein: RN recip + 2 fma) == __fdiv_rn
__device__ __forceinline__ float div_sr(float x) {
  float q0 = __fmul_rn(x, INV_SR);
  float e  = __builtin_fmaf(-44100.0f, q0, x);
  return __builtin_fmaf(e, INV_SR, q0);
}

// sin of the fp32 value x (|x| up to ~3e5): float Cody-Waite reduce + v_sin.
__device__ __forceinline__ float sin_fast(float x) {
  float k = rintf(__fmul_rn(x, INV2PI_F));
  float r = __builtin_fmaf(-k, PI2_HI, x);
  r = __builtin_fmaf(-k, PI2_LO, r);
  return __sinf(r);
}

// f0 Hz from normalized (identical op chain to the old k_f0)
__device__ __forceinline__ float f0_hz(float fn, float C1, float C2) {
  float x = __fadd_rn(__fmul_rn(fn, C1), C2);
  return (float)exp2((double)x);
}

// ---------------- MLP layer 1: hp/hn = relu(z @ W1{p,n} + b) ----------------
__global__ __launch_bounds__(256) void k_mlp1(
    const float* __restrict__ z,
    const float* __restrict__ W1p, const float* __restrict__ b1p,
    const float* __restrict__ W1n, const float* __restrict__ b1n,
    float* __restrict__ hp, float* __restrict__ hn) {
  int ct = blockIdx.x;               // col tile 0..3
  int rt = blockIdx.y;               // row tile 0..62
  int tid = threadIdx.x;
  int tx = tid & 15, ty = tid >> 4;
  int col0 = ct * 64 + tx * 4;
  int row0 = rt * 64 + ty * 4;
  __shared__ float zs[64][129];      // padded: conflict-free column reads
  for (int i = tid; i < 64 * 32; i += 256) {
    int r = i >> 5, q = (i & 31) * 4;
    int gr = rt * 64 + r; if (gr > 3999) gr = 3999;
    float4 v = *(const float4*)&z[(size_t)gr * ND + q];
    zs[r][q] = v.x; zs[r][q + 1] = v.y; zs[r][q + 2] = v.z; zs[r][q + 3] = v.w;
  }
  __syncthreads();
  float accp[4][4], accn[4][4];
#pragma unroll
  for (int c = 0; c < 4; ++c) {
    float bp = b1p[col0 + c], bn = b1n[col0 + c];
#pragma unroll
    for (int r = 0; r < 4; ++r) { accp[r][c] = bp; accn[r][c] = bn; }
  }
#pragma unroll 2
  for (int d = 0; d < ND; ++d) {
    float4 wp = *(const float4*)&W1p[d * 256 + col0];
    float4 wn = *(const float4*)&W1n[d * 256 + col0];
    float zv[4];
#pragma unroll
    for (int r = 0; r < 4; ++r) zv[r] = zs[ty * 4 + r][d];
#pragma unroll
    for (int r = 0; r < 4; ++r) {
      accp[r][0] = fmaf(zv[r], wp.x, accp[r][0]);
      accp[r][1] = fmaf(zv[r], wp.y, accp[r][1]);
      accp[r][2] = fmaf(zv[r], wp.z, accp[r][2]);
      accp[r][3] = fmaf(zv[r], wp.w, accp[r][3]);
      accn[r][0] = fmaf(zv[r], wn.x, accn[r][0]);
      accn[r][1] = fmaf(zv[r], wn.y, accn[r][1]);
      accn[r][2] = fmaf(zv[r], wn.z, accn[r][2]);
      accn[r][3] = fmaf(zv[r], wn.w, accn[r][3]);
    }
  }
#pragma unroll
  for (int r = 0; r < 4; ++r) {
    int gr = row0 + r;
    if (gr < 4000) {
      float4 op = make_float4(fmaxf(accp[r][0], 0.0f), fmaxf(accp[r][1], 0.0f),
                              fmaxf(accp[r][2], 0.0f), fmaxf(accp[r][3], 0.0f));
      float4 on = make_float4(fmaxf(accn[r][0], 0.0f), fmaxf(accn[r][1], 0.0f),
                              fmaxf(accn[r][2], 0.0f), fmaxf(accn[r][3], 0.0f));
      *(float4*)&hp[(size_t)gr * 256 + col0] = op;
      *(float4*)&hn[(size_t)gr * 256 + col0] = on;
    }
  }
}

// ---------------- MLP layer 2: nmag = sigmoid(hn@W2n+b), amp = sigmoid(hp@W2p+b) ----
__global__ __launch_bounds__(256) void k_mlp2(
    const float* __restrict__ hp, const float* __restrict__ hn,
    const float* __restrict__ W2p, const float* __restrict__ b2p,
    const float* __restrict__ W2n, const float* __restrict__ b2n,
    float* __restrict__ amp, float* __restrict__ nmag) {
  int ct = blockIdx.x;               // 0..4
  int rt = blockIdx.y;               // 0..62
  int tid = threadIdx.x;
  int tx = tid & 15, ty = tid >> 4;
  bool isAmp = (ct == 4);
  const float* hsrc = isAmp ? hp : hn;
  const float* Wsrc = isAmp ? W2p : W2n;
  const float* bias = isAmp ? b2p : b2n;
  int ncols = isAmp ? 64 : 256;
  int col0 = isAmp ? tx * 4 : ct * 64 + tx * 4;
  int row0 = rt * 64 + ty * 4;
  __shared__ float hs[64][129];
  float acc[4][4];
#pragma unroll
  for (int c = 0; c < 4; ++c) {
    float bv = bias[col0 + c];
#pragma unroll
    for (int r = 0; r < 4; ++r) acc[r][c] = bv;
  }
  for (int kc = 0; kc < 2; ++kc) {
    for (int i = tid; i < 64 * 32; i += 256) {
      int r = i >> 5, q = (i & 31) * 4;
      int gr = rt * 64 + r; if (gr > 3999) gr = 3999;
      float4 v = *(const float4*)&hsrc[(size_t)gr * 256 + kc * 128 + q];
      hs[r][q] = v.x; hs[r][q + 1] = v.y; hs[r][q + 2] = v.z; hs[r][q + 3] = v.w;
    }
    __syncthreads();
#pragma unroll 4
    for (int d = 0; d < 128; ++d) {
      float4 w = *(const float4*)&Wsrc[(size_t)(kc * 128 + d) * ncols + col0];
      float hv[4];
#pragma unroll
      for (int r = 0; r < 4; ++r) hv[r] = hs[ty * 4 + r][d];
#pragma unroll
      for (int r = 0; r < 4; ++r) {
        acc[r][0] = fmaf(hv[r], w.x, acc[r][0]);
        acc[r][1] = fmaf(hv[r], w.y, acc[r][1]);
        acc[r][2] = fmaf(hv[r], w.z, acc[r][2]);
        acc[r][3] = fmaf(hv[r], w.w, acc[r][3]);
      }
    }
    __syncthreads();
  }
#pragma unroll
  for (int r = 0; r < 4; ++r) {
    int gr = row0 + r;
    if (gr < 4000) {
      float4 o = make_float4(1.0f / (1.0f + expf(-acc[r][0])),
                             1.0f / (1.0f + expf(-acc[r][1])),
                             1.0f / (1.0f + expf(-acc[r][2])),
                             1.0f / (1.0f + expf(-acc[r][3])));
      if (isAmp) *(float4*)&amp[(size_t)gr * 64 + col0] = o;
      else       *(float4*)&nmag[(size_t)gr * 256 + col0] = o;
    }
  }
}

// ---------------- mean stage 1 (80 blocks of 50 frames) ----------------
__global__ __launch_bounds__(256) void k_mean1(const float* __restrict__ nmag,
                                               float* __restrict__ mmpart) {
  int b = blockIdx.x, seg = blockIdx.y;     // 10 segments of 50 frames
  int k = threadIdx.x;
  float s = 0.0f;
  int t0 = seg * 50;
  for (int t = t0; t < t0 + 50; ++t) s += nmag[((size_t)b * NT + t) * 256 + k];
  mmpart[((size_t)b * 10 + seg) * 256 + k] = s;
}

// ---------------- basis G[s][n][i] = partial_s sum_k hat_i(k) cos(2 pi n k/88000) ----
__global__ __launch_bounds__(256) void k_basis(float* __restrict__ G) {
  int n = blockIdx.x;       // 0..LCONV
  int s = blockIdx.y;       // slice 0..BSLC-1
  int i = threadIdx.x;      // bin 0..255
  int start = 1, end = 43999;
  if (i > 0) {
    int s0 = (int)(((float)i - 0.5f) * 171.87890625f - 0.5f) - 4;
    if (s0 > start) start = s0;
  }
  int e0 = (int)(((float)i + 1.5f) * 171.87890625f - 0.5f) + 4;
  if (e0 < end) end = e0;
  int len = (end - start + BSLC) / BSLC;      // ceil
  int ks = start + s * len;
  int ke = ks + len - 1; if (ke > end) ke = end;
  float acc = 0.0f;
  if (ks <= ke) {
    int m = (int)(((long long)n * ks) % TAUD);
    for (int k = ks; k <= ke; ++k) {
      float kf  = (float)k;
      float src = __fsub_rn(__fmul_rn(__fadd_rn(kf, 0.5f), SCALE_NF), 0.5f);
      src = fminf(fmaxf(src, 0.0f), 255.0f);
      int i0 = (int)src;
      float w = __fsub_rn(src, (float)i0);
      float wt = 0.0f;
      if (i0 == i) wt = __fsub_rn(1.0f, w);
      int i1 = (i0 < 255) ? i0 + 1 : 255;
      if (i1 == i) wt = __fadd_rn(wt, w);
      acc = fmaf(wt, __cosf((float)m * CANG), acc);
      m += n; if (m >= TAUD) m -= TAUD;
    }
  }
  G[((size_t)s * (LCONV + 1) + n) * 256 + i] = acc;
}

// ---------------- combine (mean stage 2 folded in): h[b][n] ----------------
__global__ __launch_bounds__(256) void k_hc(const float* __restrict__ mmpart,
                                            const float* __restrict__ G,
                                            float* __restrict__ hh) {
  int n = blockIdx.x;       // 0..LCONV
  int b = blockIdx.y;       // batch
  int tid = threadIdx.x;
  __shared__ float mmS[256];
  // mean stage 2 (same ascending sum + scale as the old k_mean2)
  {
    float s = 0.0f;
    for (int seg = 0; seg < 10; ++seg)
      s += mmpart[((size_t)b * 10 + seg) * 256 + tid];
    mmS[tid] = s * (1.0f / 500.0f);
  }
  const size_t GS = (size_t)(LCONV + 1) * 256;
  size_t gi = (size_t)n * 256 + tid;
  float g01 = G[gi] + G[GS + gi];
  float g23 = G[2 * GS + gi] + G[3 * GS + gi];
  float g45 = G[4 * GS + gi] + G[5 * GS + gi];
  float g67 = G[6 * GS + gi] + G[7 * GS + gi];
  float g = (g01 + g23) + (g45 + g67);
  __syncthreads();
  __shared__ float red[256];
  red[tid] = mmS[tid] * g;
  __syncthreads();
  for (int st = 128; st > 0; st >>= 1) {
    if (tid < st) red[tid] += red[tid + st];
    __syncthreads();
  }
  if (tid == 0) {
    float F0 = mmS[0];
    float src = __fsub_rn(__fmul_rn(__fadd_rn(44000.0f, 0.5f), SCALE_NF), 0.5f);
    src = fminf(fmaxf(src, 0.0f), 255.0f);
    int i0 = (int)src;
    float w = __fsub_rn(src, (float)i0);
    int i1 = (i0 < 255) ? i0 + 1 : 255;
    float FN = __fadd_rn(__fmul_rn(mmS[i0], __fsub_rn(1.0f, w)),
                         __fmul_rn(mmS[i1], w));
    float tot = 2.0f * red[0] + F0 + ((n & 1) ? -FN : FN);
    hh[b * (LCONV + 1) + n] = tot * (1.0f / 88000.0f);
  }
}

// ---------------- level-4 block sums (f0 inlined; preamble amortized) ----------
__global__ __launch_bounds__(256) void k_lev4(const float* __restrict__ f0n,
                                              float* __restrict__ lev4,
                                              float C1, float C2) {
  int chunk = blockIdx.x, b = blockIdx.y, g = blockIdx.z;
  int tid = threadIdx.x;
  int m = chunk * 256 + tid;
  bool act = (m < 5500);
  __shared__ float sf0[NT];
  for (int i = tid; i < NT; i += 256) sf0[i] = f0_hz(f0n[b * NT + i], C1, C2);
  __syncthreads();
  if (!act) return;
  int j0 = m * 16;
  float wv[16], wm[16];
  unsigned damask = 0;
  int f = 0;
#pragma unroll
  for (int t = 0; t < 16; ++t) {
    int j = j0 + t;
    float jf = (float)j;
    float src = __fsub_rn(__fmul_rn(__fadd_rn(jf, 0.5f), SCALE_TA), 0.5f);
    src = fminf(fmaxf(src, 0.0f), 499.0f);
    int a = (int)src;
    if (t == 0) f = a;
    wv[t] = __fsub_rn(src, (float)a);
    wm[t] = __fsub_rn(1.0f, wv[t]);
    damask |= (unsigned)(a - f) << t;
  }
  int f1 = (f + 1 > 499) ? 499 : f + 1;
  int f2 = (f + 2 > 499) ? 499 : f + 2;
  float s0 = sf0[f], s1 = sf0[f1], s2 = sf0[f2];
  for (int pp = 0; pp < 16; ++pp) {
    int p = g * 16 + pp;
    float pf = (float)(p + 1);
    float fs0 = __fmul_rn(s0, pf);
    float fs1 = __fmul_rn(s1, pf);
    float fs2 = __fmul_rn(s2, pf);
    float v[16];
#pragma unroll
    for (int t = 0; t < 16; ++t) {
      bool d = (damask >> t) & 1;
      float fa = d ? fs1 : fs0;
      float fb = d ? fs2 : fs1;
      float fu = __fadd_rn(__fmul_rn(fa, wm[t]), __fmul_rn(fb, wv[t]));
      v[t] = div_sr(fu);
    }
    float s1t[8];
#pragma unroll
    for (int t = 0; t < 8; ++t) s1t[t] = __fadd_rn(v[2 * t], v[2 * t + 1]);
    float s2t[4];
#pragma unroll
    for (int t = 0; t < 4; ++t) s2t[t] = __fadd_rn(s1t[2 * t], s1t[2 * t + 1]);
    float s3a = __fadd_rn(s2t[0], s2t[1]);
    float s3b = __fadd_rn(s2t[2], s2t[3]);
    lev4[((size_t)(b * NPART + p)) * 5500 + m] = __fadd_rn(s3a, s3b);
  }
}

// ---------------- scan upper levels: Brent-Kung on loaded lev4 ----------------
__global__ __launch_bounds__(256) void k_scan_rest(const float* __restrict__ lev4,
                                                   float* __restrict__ pref4) {
  int bp = blockIdx.x;
  __shared__ float lev[10992];
  int tid = threadIdx.x;
  for (int m = tid; m < 5500; m += 256) lev[m] = lev4[(size_t)bp * 5500 + m];
  __syncthreads();
  const int sizes[13] = {5500, 2750, 1375, 687, 343, 171, 85, 42, 21, 10, 5, 2, 1};
  const int offs[13]  = {0, 5500, 8250, 9625, 10312, 10655, 10826, 10911,
                         10953, 10974, 10984, 10989, 10991};
  for (int L = 1; L < 13; ++L) {
    int n = sizes[L];
    const float* src = lev + offs[L - 1];
    float* dst = lev + offs[L];
    for (int k2 = tid; k2 < n; k2 += 256)
      dst[k2] = __fadd_rn(src[2 * k2], src[2 * k2 + 1]);
    __syncthreads();
  }
  for (int L = 11; L >= 0; --L) {
    int n = sizes[L];
    float* cur = lev + offs[L];
    const float* up = lev + offs[L + 1];
    for (int idx = 1 + tid; idx < n; idx += 256) {
      float val;
      if (idx & 1) val = up[(idx - 1) >> 1];
      else         val = __fadd_rn(up[(idx >> 1) - 1], cur[idx]);
      cur[idx] = val;
    }
    __syncthreads();
  }
  for (int m = tid; m < 5500; m += 256)
    pref4[(size_t)bp * 5500 + m] = lev[m];
}

// ---------------- fused harmonic synth (f0 inlined) ----------------
__global__ __launch_bounds__(256) void k_harm(const float* __restrict__ f0n,
                                              const float* __restrict__ amp,
                                              const float* __restrict__ pref4,
                                              float* __restrict__ hpart,
                                              float C1, float C2) {
  int chunk = blockIdx.x, b = blockIdx.y, g = blockIdx.z;
  int tid = threadIdx.x;
  int m = chunk * 256 + tid;
  bool act = (m < 5500);
  __shared__ float sf0[NT];
  for (int i = tid; i < NT; i += 256) sf0[i] = f0_hz(f0n[b * NT + i], C1, C2);
  __syncthreads();
  int mm_ = act ? m : 0;
  int j0 = mm_ * 16;
  float wv[16], wm[16];
  unsigned damask = 0, dnmask = 0;
  int f = 0;
#pragma unroll
  for (int t = 0; t < 16; ++t) {
    int j = j0 + t;
    float jf = (float)j;
    float src = __fsub_rn(__fmul_rn(__fadd_rn(jf, 0.5f), SCALE_TA), 0.5f);
    src = fminf(fmaxf(src, 0.0f), 499.0f);
    int a = (int)src;
    if (t == 0) f = a;                 // i0 monotone nondecreasing in j
    wv[t] = __fsub_rn(src, (float)a);
    wm[t] = __fsub_rn(1.0f, wv[t]);
    damask |= (unsigned)(a - f) << t;  // in {0,1}
    int ni = (int)__fmul_rn(jf, SCALE_TA);
    ni = ni > 499 ? 499 : ni;
    dnmask |= (unsigned)(ni - f) << t; // in {0,1}
  }
  int f1 = (f + 1 > 499) ? 499 : f + 1;
  int f2 = (f + 2 > 499) ? 499 : f + 2;
  float s0 = sf0[f], s1 = sf0[f1], s2 = sf0[f2];

  float acc[16];
#pragma unroll
  for (int t = 0; t < 16; ++t) acc[t] = 0.0f;

  for (int pp = 0; pp < 16; ++pp) {
    int p = g * 16 + pp;
    float pf = (float)(p + 1);
    float fs0 = __fmul_rn(s0, pf);
    float fs1 = __fmul_rn(s1, pf);
    if (!(fs0 < 22050.0f) && !(fs1 < 22050.0f)) break;
    float fs2 = __fmul_rn(s2, pf);
    size_t pbase = ((size_t)(b * NPART + p)) * 5500;
    float left = (mm_ > 0) ? pref4[pbase + mm_ - 1] : 0.0f;
    float P4 = pref4[pbase + mm_];
    float v[16];
#pragma unroll
    for (int t = 0; t < 16; ++t) {
      bool d = (damask >> t) & 1;
      float fa = d ? fs1 : fs0;
      float fb = d ? fs2 : fs1;
      float fu = __fadd_rn(__fmul_rn(fa, wm[t]), __fmul_rn(fb, wv[t]));
      v[t] = div_sr(fu);
    }
    float s1t[8];
#pragma unroll
    for (int t = 0; t < 8; ++t) s1t[t] = __fadd_rn(v[2 * t], v[2 * t + 1]);
    float s2t[4];
#pragma unroll
    for (int t = 0; t < 4; ++t) s2t[t] = __fadd_rn(s1t[2 * t], s1t[2 * t + 1]);
    float s3_0 = __fadd_rn(s2t[0], s2t[1]);
    bool fz = (mm_ == 0);
    float l3_0 = fz ? s3_0 : __fadd_rn(left, s3_0);
    float l2_0 = fz ? s2t[0] : __fadd_rn(left, s2t[0]);
    float l2_1 = l3_0;
    float l2_2 = __fadd_rn(l3_0, s2t[2]);
    float l2_3 = P4;
    float l1_0 = fz ? s1t[0] : __fadd_rn(left, s1t[0]);
    float l1_1 = l2_0;
    float l1_2 = __fadd_rn(l2_0, s1t[2]);
    float l1_3 = l2_1;
    float l1_4 = __fadd_rn(l2_1, s1t[4]);
    float l1_5 = l2_2;
    float l1_6 = __fadd_rn(l2_2, s1t[6]);
    float l1_7 = l2_3;
    float ph[16];
    ph[0]  = fz ? v[0] : __fadd_rn(left, v[0]);
    ph[1]  = l1_0;
    ph[2]  = __fadd_rn(l1_0, v[2]);
    ph[3]  = l1_1;
    ph[4]  = __fadd_rn(l1_1, v[4]);
    ph[5]  = l1_2;
    ph[6]  = __fadd_rn(l1_2, v[6]);
    ph[7]  = l1_3;
    ph[8]  = __fadd_rn(l1_3, v[8]);
    ph[9]  = l1_4;
    ph[10] = __fadd_rn(l1_4, v[10]);
    ph[11] = l1_5;
    ph[12] = __fadd_rn(l1_5, v[12]);
    ph[13] = l1_6;
    ph[14] = __fadd_rn(l1_6, v[14]);
    ph[15] = l1_7;
    float ga0 = amp[((size_t)(b * NT + f)) * 64 + p];
    float ga1 = amp[((size_t)(b * NT + f1)) * 64 + p];
    float ga2 = amp[((size_t)(b * NT + f2)) * 64 + p];
#pragma unroll
    for (int t = 0; t < 16; ++t) {
      bool dn = (dnmask >> t) & 1;
      float fr = dn ? fs1 : fs0;
      if (fr < 22050.0f) {
        float x = __fmul_rn(ph[t], TWOPI_F);
        float s = sin_fast(x);
        bool d = (damask >> t) & 1;
        float lo = d ? ga1 : ga0;
        float hi = d ? ga2 : ga1;
        float au = __builtin_fmaf(__fsub_rn(hi, lo), wv[t], lo);
        acc[t] = __builtin_fmaf(s, au, acc[t]);
      }
    }
  }
  if (act) {
    size_t obase = ((size_t)g * NBATCH + b) * TAUD + (size_t)j0;
#pragma unroll
    for (int t = 0; t < 16; ++t) hpart[obase + t] = acc[t];
  }
}

// ---------------- circular convolution + final mix (fused) ----------------
#define CT    1024
#define PSTR  392
__global__ __launch_bounds__(256) void k_convfinal(const float* __restrict__ noise,
                                                   const float* __restrict__ hh,
                                                   const float* __restrict__ hpart,
                                                   const float* __restrict__ loud,
                                                   float* __restrict__ out) {
  int b = blockIdx.y;
  int t0 = blockIdx.x * CT;
  int tid = threadIdx.x;
  __shared__ float xsp[4 * PSTR];     // window x[t0-256 .. t0+CT+256)
  __shared__ float hsh[LCONV];        // h[1..256]
  const float* hb = hh + b * (LCONV + 1);
  for (int i = tid; i < CT + 2 * LCONV; i += 256) {
    int j = t0 - LCONV + i;
    if (j < 0) j += TAUD;
    else if (j >= TAUD) j -= TAUD;
    xsp[(i & 3) * PSTR + (i >> 2)] = noise[(size_t)b * TAUD + j];
  }
  hsh[tid] = hb[1 + tid];             // LCONV == blockDim == 256
  __syncthreads();
  float h0 = hb[0];
  int B4 = tid + 64;                  // plane row of x[t0 + 4*tid]
  float a0 = h0 * xsp[0 * PSTR + B4];
  float a1 = h0 * xsp[1 * PSTR + B4];
  float a2 = h0 * xsp[2 * PSTR + B4];
  float a3 = h0 * xsp[3 * PSTR + B4];
  for (int g = 0; g < 32; ++g) {      // taps d = 8g+1 .. 8g+8
    int km = tid + 62 - 2 * g;        // minus side base (plane k)
    int kp = tid + 64 + 2 * g;        // plus side base
    float mv0 = xsp[0 * PSTR + km],     mv1 = xsp[1 * PSTR + km];
    float mv2 = xsp[2 * PSTR + km],     mv3 = xsp[3 * PSTR + km];
    float mv4 = xsp[0 * PSTR + km + 1], mv5 = xsp[1 * PSTR + km + 1];
    float mv6 = xsp[2 * PSTR + km + 1], mv7 = xsp[3 * PSTR + km + 1];
    float mv8 = xsp[0 * PSTR + km + 2], mv9 = xsp[1 * PSTR + km + 2];
    float mv10 = xsp[2 * PSTR + km + 2];
    float pv1 = xsp[1 * PSTR + kp],     pv2 = xsp[2 * PSTR + kp];
    float pv3 = xsp[3 * PSTR + kp];
    float pv4 = xsp[0 * PSTR + kp + 1], pv5 = xsp[1 * PSTR + kp + 1];
    float pv6 = xsp[2 * PSTR + kp + 1], pv7 = xsp[3 * PSTR + kp + 1];
    float pv8 = xsp[0 * PSTR + kp + 2], pv9 = xsp[1 * PSTR + kp + 2];
    float pv10 = xsp[2 * PSTR + kp + 2], pv11 = xsp[3 * PSTR + kp + 2];
    int hbase = 8 * g;                // uniform -> broadcast reads
    float hv0 = hsh[hbase + 0], hv1 = hsh[hbase + 1];
    float hv2 = hsh[hbase + 2], hv3 = hsh[hbase + 3];
    float hv4 = hsh[hbase + 4], hv5 = hsh[hbase + 5];
    float hv6 = hsh[hbase + 6], hv7 = hsh[hbase + 7];
    a0 = fmaf(hv0, mv7 + pv1, a0);
    a0 = fmaf(hv1, mv6 + pv2, a0);
    a0 = fmaf(hv2, mv5 + pv3, a0);
    a0 = fmaf(hv3, mv4 + pv4, a0);
    a0 = fmaf(hv4, mv3 + pv5, a0);
    a0 = fmaf(hv5, mv2 + pv6, a0);
    a0 = fmaf(hv6, mv1 + pv7, a0);
    a0 = fmaf(hv7, mv0 + pv8, a0);
    a1 = fmaf(hv0, mv8 + pv2, a1);
    a1 = fmaf(hv1, mv7 + pv3, a1);
    a1 = fmaf(hv2, mv6 + pv4, a1);
    a1 = fmaf(hv3, mv5 + pv5, a1);
    a1 = fmaf(hv4, mv4 + pv6, a1);
    a1 = fmaf(hv5, mv3 + pv7, a1);
    a1 = fmaf(hv6, mv2 + pv8, a1);
    a1 = fmaf(hv7, mv1 + pv9, a1);
    a2 = fmaf(hv0, mv9 + pv3, a2);
    a2 = fmaf(hv1, mv8 + pv4, a2);
    a2 = fmaf(hv2, mv7 + pv5, a2);
    a2 = fmaf(hv3, mv6 + pv6, a2);
    a2 = fmaf(hv4, mv5 + pv7, a2);
    a2 = fmaf(hv5, mv4 + pv8, a2);
    a2 = fmaf(hv6, mv3 + pv9, a2);
    a2 = fmaf(hv7, mv2 + pv10, a2);
    a3 = fmaf(hv0, mv10 + pv4, a3);
    a3 = fmaf(hv1, mv9 + pv5, a3);
    a3 = fmaf(hv2, mv8 + pv6, a3);
    a3 = fmaf(hv3, mv7 + pv7, a3);
    a3 = fmaf(hv4, mv6 + pv8, a3);
    a3 = fmaf(hv5, mv5 + pv9, a3);
    a3 = fmaf(hv6, mv4 + pv10, a3);
    a3 = fmaf(hv7, mv3 + pv11, a3);
  }
  int t = t0 + tid * 4;
  if (t < TAUD) {                     // TAUD%4==0 -> all 4 valid together
    const size_t S = (size_t)NBATCH * TAUD;
    size_t base = (size_t)b * TAUD + t;
    float4 h0v = *(const float4*)&hpart[base];
    float4 h1v = *(const float4*)&hpart[S + base];
    float4 h2v = *(const float4*)&hpart[2 * S + base];
    float4 h3v = *(const float4*)&hpart[3 * S + base];
    float yn[4] = {a0 * 0.1f, a1 * 0.1f, a2 * 0.1f, a3 * 0.1f};
    float hs0[4] = {h0v.x, h0v.y, h0v.z, h0v.w};
    float hs1[4] = {h1v.x, h1v.y, h1v.z, h1v.w};
    float hs2[4] = {h2v.x, h2v.y, h2v.z, h2v.w};
    float hs3[4] = {h3v.x, h3v.y, h3v.z, h3v.w};
    float o[4];
#pragma unroll
    for (int u = 0; u < 4; ++u) {
      int j = t + u;
      int i0, i1; float w;
      iparams(j, i0, i1, w);
      float env = __fadd_rn(__fmul_rn(loud[b * NT + i0], __fsub_rn(1.0f, w)),
                            __fmul_rn(loud[b * NT + i1], w));
      float hsum = __fadd_rn(__fadd_rn(__fadd_rn(hs0[u], hs1[u]), hs2[u]), hs3[u]);
      o[u] = __fmul_rn(__fadd_rn(hsum, yn[u]), env);
    }
    *reinterpret_cast<float4*>(&out[base]) = make_float4(o[0], o[1], o[2], o[3]);
  }
}

}  // namespace

extern "C" void kernel_launch(void* const* d_in, const int* in_sizes, int n_in,
                              void* d_out, int out_size, void* d_ws, size_t ws_size,
                              hipStream_t stream) {
  const float* z    = (const float*)d_in[0];
  const float* f0n  = (const float*)d_in[1];
  const float* loud = (const float*)d_in[2];
  const float* nz   = (const float*)d_in[3];
  const float* W1p  = (const float*)d_in[4];
  const float* b1p  = (const float*)d_in[5];
  const float* W2p  = (const float*)d_in[6];
  const float* b2p  = (const float*)d_in[7];
  const float* W1n  = (const float*)d_in[8];
  const float* b1n  = (const float*)d_in[9];
  const float* W2n  = (const float*)d_in[10];
  const float* b2n  = (const float*)d_in[11];
  float* out = (float*)d_out;
  float* ws  = (float*)d_ws;

  size_t off = 0;
  float* amp    = ws + off; off += (size_t)NBATCH * NT * NPART;          // 256,000
  float* nmag   = ws + off; off += (size_t)NBATCH * NT * NBINS;          // 1,024,000
  float* mmpart = ws + off; off += (size_t)NBATCH * 10 * NBINS;          // 20,480
  float* G      = ws + off; off += (size_t)BSLC * (LCONV + 1) * NBINS;   // 526,336
  float* hh     = ws + off; off += (size_t)NBATCH * (LCONV + 1);         // 2,056
  float* lev4   = ws + off; off += (size_t)NBATCH * NPART * 5500;        // 2,816,000
  float* pref4  = ws + off; off += (size_t)NBATCH * NPART * 5500;        // 2,816,000
  float* hpart  = ws + off; off += (size_t)4 * NBATCH * TAUD;            // 2,816,000
  (void)ws_size; (void)in_sizes; (void)n_in; (void)out_size;             // ~41 MB total

  // hp/hn alias hpart: consumed by k_mlp2 before k_harm overwrites hpart.
  float* hp = hpart;                      // 1,024,000 floats
  float* hn = hpart + (size_t)1024000;    // 1,024,000 floats (< 2,816,000)

  double HI = log2(2093.0), LO = log2(32.7);
  float C1 = (float)(HI - LO), C2 = (float)LO;

  dim3 gb(LCONV + 1, BSLC);
  k_basis<<<gb, 256, 0, stream>>>(G);
  dim3 g1(4, 63);
  k_mlp1<<<g1, 256, 0, stream>>>(z, W1p, b1p, W1n, b1n, hp, hn);
  dim3 g2(5, 63);
  k_mlp2<<<g2, 256, 0, stream>>>(hp, hn, W2p, b2p, W2n, b2n, amp, nmag);
  dim3 gm(NBATCH, 10);
  k_mean1<<<gm, 256, 0, stream>>>(nmag, mmpart);
  dim3 ghc(LCONV + 1, NBATCH);
  k_hc<<<ghc, 256, 0, stream>>>(mmpart, G, hh);
  dim3 gl(22, NBATCH, 4);
  k_lev4<<<gl, 256, 0, stream>>>(f0n, lev4, C1, C2);
  k_scan_rest<<<NBATCH * NPART, 256, 0, stream>>>(lev4, pref4);
  dim3 gh(22, NBATCH, 4);
  k_harm<<<gh, 256, 0, stream>>>(f0n, amp, pref4, hpart, C1, C2);
  dim3 gc((TAUD + CT - 1) / CT, NBATCH);
  k_convfinal<<<gc, 256, 0, stream>>>(nz, hh, hpart, loud, out);
}

// Round 14
// 152.941 us; speedup vs baseline: 1.3779x; 1.0615x over previous
//
#include <hip/hip_runtime.h>
#include <cmath>

// DDSP decoder, bit-exact-phase implementation.
// R14: occupancy push. MLP tiles 64x64 -> 32x64 (252/315 -> 500/625 blocks,
//      ~1 -> ~2+ waves/SIMD; per-output op chain unchanged -> bit-identical).
//      k_harm partial groups 4 -> 8 (704 -> 1408 blocks, 5.5 w/SIMD); hpart
//      8 slices, convfinal sums ascending (partial-sum order ~1e-6 shift,
//      never JAX-matched). Phase path untouched.

#define NBATCH 8
#define NT     500
#define ND     128
#define TAUD   88000
#define NPART  64
#define NBINS  256
#define NFREQ  44001
#define LCONV  256
#define BSLC   8
#define NPG    8        // harm partial groups
#define PPG    8        // partials per group

namespace {

constexpr float  SCALE_TA = (float)(500.0 / 88000.0);   // lin_interp scale, fp32 like jnp
constexpr float  SCALE_NF = (float)(256.0 / 44001.0);
constexpr float  TWOPI_F  = (float)6.283185307179586476925286766559;
constexpr float  CANG     = (float)(6.283185307179586476925286766559 / 88000.0);
constexpr float  INV_SR   = 1.0f / 44100.0f;            // RN reciprocal
constexpr float  INV2PI_F = 0.15915494309189535f;       // RN(1/2pi)
constexpr float  PI2_HI   = 6.2831854820251464844f;     // RN(2pi) fp32
constexpr float  PI2_LO   = -1.7484556000744487e-7f;    // RN(2pi - PI2_HI)

__device__ __forceinline__ void iparams(int j, int& i0, int& i1, float& w) {
  float jf  = (float)j;
  float src = __fsub_rn(__fmul_rn(__fadd_rn(jf, 0.5f), SCALE_TA), 0.5f);
  src = fminf(fmaxf(src, 0.0f), 499.0f);
  int a = (int)src;            // floor (src >= 0)
  i0 = a;
  i1 = (a + 1 > 499) ? 499 : (a + 1);
  w  = __fsub_rn(src, (float)a);
}

// correctly-rounded x/44100 (Markstein: RN recip + 2 fma) == __fdiv_rn
__device__ __forceinline__ float div_sr(float x) {
  float q0 = __fmul_rn(x, INV_SR);
  float e  = __builtin_fmaf(-44100.0f, q0, x);
  return __builtin_fmaf(e, INV_SR, q0);
}

// sin of the fp32 value x (|x| up to ~3e5): float Cody-Waite reduce + v_sin.
__device__ __forceinline__ float sin_fast(float x) {
  float k = rintf(__fmul_rn(x, INV2PI_F));
  float r = __builtin_fmaf(-k, PI2_HI, x);
  r = __builtin_fmaf(-k, PI2_LO, r);
  return __sinf(r);
}

// f0 Hz from normalized (identical op chain to the original k_f0)
__device__ __forceinline__ float f0_hz(float fn, float C1, float C2) {
  float x = __fadd_rn(__fmul_rn(fn, C1), C2);
  return (float)exp2((double)x);
}

// ---------------- MLP layer 1: hp/hn = relu(z @ W1{p,n} + b) ----------------
// 32 rows x 64 cols per block; thread (tx,ty) owns 4 cols x 2 rows.
__global__ __launch_bounds__(256) void k_mlp1(
    const float* __restrict__ z,
    const float* __restrict__ W1p, const float* __restrict__ b1p,
    const float* __restrict__ W1n, const float* __restrict__ b1n,
    float* __restrict__ hp, float* __restrict__ hn) {
  int ct = blockIdx.x;               // col tile 0..3
  int rt = blockIdx.y;               // row tile 0..124
  int tid = threadIdx.x;
  int tx = tid & 15, ty = tid >> 4;
  int col0 = ct * 64 + tx * 4;
  int row0 = rt * 32 + ty * 2;
  __shared__ float zs[32][129];      // padded: conflict-free column reads
  for (int i = tid; i < 32 * 32; i += 256) {
    int r = i >> 5, q = (i & 31) * 4;
    int gr = rt * 32 + r;            // 125*32 = 4000 exact
    float4 v = *(const float4*)&z[(size_t)gr * ND + q];
    zs[r][q] = v.x; zs[r][q + 1] = v.y; zs[r][q + 2] = v.z; zs[r][q + 3] = v.w;
  }
  __syncthreads();
  float accp[2][4], accn[2][4];
#pragma unroll
  for (int c = 0; c < 4; ++c) {
    float bp = b1p[col0 + c], bn = b1n[col0 + c];
#pragma unroll
    for (int r = 0; r < 2; ++r) { accp[r][c] = bp; accn[r][c] = bn; }
  }
#pragma unroll 4
  for (int d = 0; d < ND; ++d) {
    float4 wp = *(const float4*)&W1p[d * 256 + col0];
    float4 wn = *(const float4*)&W1n[d * 256 + col0];
    float zv[2];
#pragma unroll
    for (int r = 0; r < 2; ++r) zv[r] = zs[ty * 2 + r][d];
#pragma unroll
    for (int r = 0; r < 2; ++r) {
      accp[r][0] = fmaf(zv[r], wp.x, accp[r][0]);
      accp[r][1] = fmaf(zv[r], wp.y, accp[r][1]);
      accp[r][2] = fmaf(zv[r], wp.z, accp[r][2]);
      accp[r][3] = fmaf(zv[r], wp.w, accp[r][3]);
      accn[r][0] = fmaf(zv[r], wn.x, accn[r][0]);
      accn[r][1] = fmaf(zv[r], wn.y, accn[r][1]);
      accn[r][2] = fmaf(zv[r], wn.z, accn[r][2]);
      accn[r][3] = fmaf(zv[r], wn.w, accn[r][3]);
    }
  }
#pragma unroll
  for (int r = 0; r < 2; ++r) {
    int gr = row0 + r;
    float4 op = make_float4(fmaxf(accp[r][0], 0.0f), fmaxf(accp[r][1], 0.0f),
                            fmaxf(accp[r][2], 0.0f), fmaxf(accp[r][3], 0.0f));
    float4 on = make_float4(fmaxf(accn[r][0], 0.0f), fmaxf(accn[r][1], 0.0f),
                            fmaxf(accn[r][2], 0.0f), fmaxf(accn[r][3], 0.0f));
    *(float4*)&hp[(size_t)gr * 256 + col0] = op;
    *(float4*)&hn[(size_t)gr * 256 + col0] = on;
  }
}

// ---------------- MLP layer 2: nmag = sigmoid(hn@W2n+b), amp = sigmoid(hp@W2p+b) ----
__global__ __launch_bounds__(256) void k_mlp2(
    const float* __restrict__ hp, const float* __restrict__ hn,
    const float* __restrict__ W2p, const float* __restrict__ b2p,
    const float* __restrict__ W2n, const float* __restrict__ b2n,
    float* __restrict__ amp, float* __restrict__ nmag) {
  int ct = blockIdx.x;               // 0..4
  int rt = blockIdx.y;               // 0..124
  int tid = threadIdx.x;
  int tx = tid & 15, ty = tid >> 4;
  bool isAmp = (ct == 4);
  const float* hsrc = isAmp ? hp : hn;
  const float* Wsrc = isAmp ? W2p : W2n;
  const float* bias = isAmp ? b2p : b2n;
  int ncols = isAmp ? 64 : 256;
  int col0 = isAmp ? tx * 4 : ct * 64 + tx * 4;
  int row0 = rt * 32 + ty * 2;
  __shared__ float hs[32][129];
  float acc[2][4];
#pragma unroll
  for (int c = 0; c < 4; ++c) {
    float bv = bias[col0 + c];
#pragma unroll
    for (int r = 0; r < 2; ++r) acc[r][c] = bv;
  }
  for (int kc = 0; kc < 2; ++kc) {
    for (int i = tid; i < 32 * 32; i += 256) {
      int r = i >> 5, q = (i & 31) * 4;
      int gr = rt * 32 + r;
      float4 v = *(const float4*)&hsrc[(size_t)gr * 256 + kc * 128 + q];
      hs[r][q] = v.x; hs[r][q + 1] = v.y; hs[r][q + 2] = v.z; hs[r][q + 3] = v.w;
    }
    __syncthreads();
#pragma unroll 4
    for (int d = 0; d < 128; ++d) {
      float4 w = *(const float4*)&Wsrc[(size_t)(kc * 128 + d) * ncols + col0];
      float hv[2];
#pragma unroll
      for (int r = 0; r < 2; ++r) hv[r] = hs[ty * 2 + r][d];
#pragma unroll
      for (int r = 0; r < 2; ++r) {
        acc[r][0] = fmaf(hv[r], w.x, acc[r][0]);
        acc[r][1] = fmaf(hv[r], w.y, acc[r][1]);
        acc[r][2] = fmaf(hv[r], w.z, acc[r][2]);
        acc[r][3] = fmaf(hv[r], w.w, acc[r][3]);
      }
    }
    __syncthreads();
  }
#pragma unroll
  for (int r = 0; r < 2; ++r) {
    int gr = row0 + r;
    float4 o = make_float4(1.0f / (1.0f + expf(-acc[r][0])),
                           1.0f / (1.0f + expf(-acc[r][1])),
                           1.0f / (1.0f + expf(-acc[r][2])),
                           1.0f / (1.0f + expf(-acc[r][3])));
    if (isAmp) *(float4*)&amp[(size_t)gr * 64 + col0] = o;
    else       *(float4*)&nmag[(size_t)gr * 256 + col0] = o;
  }
}

// ---------------- mean stage 1 (80 blocks of 50 frames) ----------------
__global__ __launch_bounds__(256) void k_mean1(const float* __restrict__ nmag,
                                               float* __restrict__ mmpart) {
  int b = blockIdx.x, seg = blockIdx.y;     // 10 segments of 50 frames
  int k = threadIdx.x;
  float s = 0.0f;
  int t0 = seg * 50;
  for (int t = t0; t < t0 + 50; ++t) s += nmag[((size_t)b * NT + t) * 256 + k];
  mmpart[((size_t)b * 10 + seg) * 256 + k] = s;
}

// ---------------- basis G[s][n][i] = partial_s sum_k hat_i(k) cos(2 pi n k/88000) ----
__global__ __launch_bounds__(256) void k_basis(float* __restrict__ G) {
  int n = blockIdx.x;       // 0..LCONV
  int s = blockIdx.y;       // slice 0..BSLC-1
  int i = threadIdx.x;      // bin 0..255
  int start = 1, end = 43999;
  if (i > 0) {
    int s0 = (int)(((float)i - 0.5f) * 171.87890625f - 0.5f) - 4;
    if (s0 > start) start = s0;
  }
  int e0 = (int)(((float)i + 1.5f) * 171.87890625f - 0.5f) + 4;
  if (e0 < end) end = e0;
  int len = (end - start + BSLC) / BSLC;      // ceil
  int ks = start + s * len;
  int ke = ks + len - 1; if (ke > end) ke = end;
  float acc = 0.0f;
  if (ks <= ke) {
    int m = (int)(((long long)n * ks) % TAUD);
    for (int k = ks; k <= ke; ++k) {
      float kf  = (float)k;
      float src = __fsub_rn(__fmul_rn(__fadd_rn(kf, 0.5f), SCALE_NF), 0.5f);
      src = fminf(fmaxf(src, 0.0f), 255.0f);
      int i0 = (int)src;
      float w = __fsub_rn(src, (float)i0);
      float wt = 0.0f;
      if (i0 == i) wt = __fsub_rn(1.0f, w);
      int i1 = (i0 < 255) ? i0 + 1 : 255;
      if (i1 == i) wt = __fadd_rn(wt, w);
      acc = fmaf(wt, __cosf((float)m * CANG), acc);
      m += n; if (m >= TAUD) m -= TAUD;
    }
  }
  G[((size_t)s * (LCONV + 1) + n) * 256 + i] = acc;
}

// ---------------- combine (mean stage 2 folded in): h[b][n] ----------------
__global__ __launch_bounds__(256) void k_hc(const float* __restrict__ mmpart,
                                            const float* __restrict__ G,
                                            float* __restrict__ hh) {
  int n = blockIdx.x;       // 0..LCONV
  int b = blockIdx.y;       // batch
  int tid = threadIdx.x;
  __shared__ float mmS[256];
  {
    float s = 0.0f;
    for (int seg = 0; seg < 10; ++seg)
      s += mmpart[((size_t)b * 10 + seg) * 256 + tid];
    mmS[tid] = s * (1.0f / 500.0f);
  }
  const size_t GS = (size_t)(LCONV + 1) * 256;
  size_t gi = (size_t)n * 256 + tid;
  float g01 = G[gi] + G[GS + gi];
  float g23 = G[2 * GS + gi] + G[3 * GS + gi];
  float g45 = G[4 * GS + gi] + G[5 * GS + gi];
  float g67 = G[6 * GS + gi] + G[7 * GS + gi];
  float g = (g01 + g23) + (g45 + g67);
  __syncthreads();
  __shared__ float red[256];
  red[tid] = mmS[tid] * g;
  __syncthreads();
  for (int st = 128; st > 0; st >>= 1) {
    if (tid < st) red[tid] += red[tid + st];
    __syncthreads();
  }
  if (tid == 0) {
    float F0 = mmS[0];
    float src = __fsub_rn(__fmul_rn(__fadd_rn(44000.0f, 0.5f), SCALE_NF), 0.5f);
    src = fminf(fmaxf(src, 0.0f), 255.0f);
    int i0 = (int)src;
    float w = __fsub_rn(src, (float)i0);
    int i1 = (i0 < 255) ? i0 + 1 : 255;
    float FN = __fadd_rn(__fmul_rn(mmS[i0], __fsub_rn(1.0f, w)),
                         __fmul_rn(mmS[i1], w));
    float tot = 2.0f * red[0] + F0 + ((n & 1) ? -FN : FN);
    hh[b * (LCONV + 1) + n] = tot * (1.0f / 88000.0f);
  }
}

// ---------------- level-4 block sums (f0 inlined; preamble amortized) ----------
__global__ __launch_bounds__(256) void k_lev4(const float* __restrict__ f0n,
                                              float* __restrict__ lev4,
                                              float C1, float C2) {
  int chunk = blockIdx.x, b = blockIdx.y, g = blockIdx.z;
  int tid = threadIdx.x;
  int m = chunk * 256 + tid;
  bool act = (m < 5500);
  __shared__ float sf0[NT];
  for (int i = tid; i < NT; i += 256) sf0[i] = f0_hz(f0n[b * NT + i], C1, C2);
  __syncthreads();
  if (!act) return;
  int j0 = m * 16;
  float wv[16], wm[16];
  unsigned damask = 0;
  int f = 0;
#pragma unroll
  for (int t = 0; t < 16; ++t) {
    int j = j0 + t;
    float jf = (float)j;
    float src = __fsub_rn(__fmul_rn(__fadd_rn(jf, 0.5f), SCALE_TA), 0.5f);
    src = fminf(fmaxf(src, 0.0f), 499.0f);
    int a = (int)src;
    if (t == 0) f = a;
    wv[t] = __fsub_rn(src, (float)a);
    wm[t] = __fsub_rn(1.0f, wv[t]);
    damask |= (unsigned)(a - f) << t;
  }
  int f1 = (f + 1 > 499) ? 499 : f + 1;
  int f2 = (f + 2 > 499) ? 499 : f + 2;
  float s0 = sf0[f], s1 = sf0[f1], s2 = sf0[f2];
  for (int pp = 0; pp < 16; ++pp) {
    int p = g * 16 + pp;
    float pf = (float)(p + 1);
    float fs0 = __fmul_rn(s0, pf);
    float fs1 = __fmul_rn(s1, pf);
    float fs2 = __fmul_rn(s2, pf);
    float v[16];
#pragma unroll
    for (int t = 0; t < 16; ++t) {
      bool d = (damask >> t) & 1;
      float fa = d ? fs1 : fs0;
      float fb = d ? fs2 : fs1;
      float fu = __fadd_rn(__fmul_rn(fa, wm[t]), __fmul_rn(fb, wv[t]));
      v[t] = div_sr(fu);
    }
    float s1t[8];
#pragma unroll
    for (int t = 0; t < 8; ++t) s1t[t] = __fadd_rn(v[2 * t], v[2 * t + 1]);
    float s2t[4];
#pragma unroll
    for (int t = 0; t < 4; ++t) s2t[t] = __fadd_rn(s1t[2 * t], s1t[2 * t + 1]);
    float s3a = __fadd_rn(s2t[0], s2t[1]);
    float s3b = __fadd_rn(s2t[2], s2t[3]);
    lev4[((size_t)(b * NPART + p)) * 5500 + m] = __fadd_rn(s3a, s3b);
  }
}

// ---------------- scan upper levels: Brent-Kung on loaded lev4 ----------------
__global__ __launch_bounds__(256) void k_scan_rest(const float* __restrict__ lev4,
                                                   float* __restrict__ pref4) {
  int bp = blockIdx.x;
  __shared__ float lev[10992];
  int tid = threadIdx.x;
  for (int m = tid; m < 5500; m += 256) lev[m] = lev4[(size_t)bp * 5500 + m];
  __syncthreads();
  const int sizes[13] = {5500, 2750, 1375, 687, 343, 171, 85, 42, 21, 10, 5, 2, 1};
  const int offs[13]  = {0, 5500, 8250, 9625, 10312, 10655, 10826, 10911,
                         10953, 10974, 10984, 10989, 10991};
  for (int L = 1; L < 13; ++L) {
    int n = sizes[L];
    const float* src = lev + offs[L - 1];
    float* dst = lev + offs[L];
    for (int k2 = tid; k2 < n; k2 += 256)
      dst[k2] = __fadd_rn(src[2 * k2], src[2 * k2 + 1]);
    __syncthreads();
  }
  for (int L = 11; L >= 0; --L) {
    int n = sizes[L];
    float* cur = lev + offs[L];
    const float* up = lev + offs[L + 1];
    for (int idx = 1 + tid; idx < n; idx += 256) {
      float val;
      if (idx & 1) val = up[(idx - 1) >> 1];
      else         val = __fadd_rn(up[(idx >> 1) - 1], cur[idx]);
      cur[idx] = val;
    }
    __syncthreads();
  }
  for (int m = tid; m < 5500; m += 256)
    pref4[(size_t)bp * 5500 + m] = lev[m];
}

// ---------------- fused harmonic synth (8 groups of 8 partials) ----------------
__global__ __launch_bounds__(256) void k_harm(const float* __restrict__ f0n,
                                              const float* __restrict__ amp,
                                              const float* __restrict__ pref4,
                                              float* __restrict__ hpart,
                                              float C1, float C2) {
  int chunk = blockIdx.x, b = blockIdx.y, g = blockIdx.z;
  int tid = threadIdx.x;
  int m = chunk * 256 + tid;
  bool act = (m < 5500);
  __shared__ float sf0[NT];
  for (int i = tid; i < NT; i += 256) sf0[i] = f0_hz(f0n[b * NT + i], C1, C2);
  __syncthreads();
  int mm_ = act ? m : 0;
  int j0 = mm_ * 16;
  float wv[16], wm[16];
  unsigned damask = 0, dnmask = 0;
  int f = 0;
#pragma unroll
  for (int t = 0; t < 16; ++t) {
    int j = j0 + t;
    float jf = (float)j;
    float src = __fsub_rn(__fmul_rn(__fadd_rn(jf, 0.5f), SCALE_TA), 0.5f);
    src = fminf(fmaxf(src, 0.0f), 499.0f);
    int a = (int)src;
    if (t == 0) f = a;                 // i0 monotone nondecreasing in j
    wv[t] = __fsub_rn(src, (float)a);
    wm[t] = __fsub_rn(1.0f, wv[t]);
    damask |= (unsigned)(a - f) << t;  // in {0,1}
    int ni = (int)__fmul_rn(jf, SCALE_TA);
    ni = ni > 499 ? 499 : ni;
    dnmask |= (unsigned)(ni - f) << t; // in {0,1}
  }
  int f1 = (f + 1 > 499) ? 499 : f + 1;
  int f2 = (f + 2 > 499) ? 499 : f + 2;
  float s0 = sf0[f], s1 = sf0[f1], s2 = sf0[f2];

  float acc[16];
#pragma unroll
  for (int t = 0; t < 16; ++t) acc[t] = 0.0f;

  for (int pp = 0; pp < PPG; ++pp) {
    int p = g * PPG + pp;
    float pf = (float)(p + 1);
    float fs0 = __fmul_rn(s0, pf);
    float fs1 = __fmul_rn(s1, pf);
    if (!(fs0 < 22050.0f) && !(fs1 < 22050.0f)) break;
    float fs2 = __fmul_rn(s2, pf);
    size_t pbase = ((size_t)(b * NPART + p)) * 5500;
    float left = (mm_ > 0) ? pref4[pbase + mm_ - 1] : 0.0f;
    float P4 = pref4[pbase + mm_];
    float v[16];
#pragma unroll
    for (int t = 0; t < 16; ++t) {
      bool d = (damask >> t) & 1;
      float fa = d ? fs1 : fs0;
      float fb = d ? fs2 : fs1;
      float fu = __fadd_rn(__fmul_rn(fa, wm[t]), __fmul_rn(fb, wv[t]));
      v[t] = div_sr(fu);
    }
    float s1t[8];
#pragma unroll
    for (int t = 0; t < 8; ++t) s1t[t] = __fadd_rn(v[2 * t], v[2 * t + 1]);
    float s2t[4];
#pragma unroll
    for (int t = 0; t < 4; ++t) s2t[t] = __fadd_rn(s1t[2 * t], s1t[2 * t + 1]);
    float s3_0 = __fadd_rn(s2t[0], s2t[1]);
    bool fz = (mm_ == 0);
    float l3_0 = fz ? s3_0 : __fadd_rn(left, s3_0);
    float l2_0 = fz ? s2t[0] : __fadd_rn(left, s2t[0]);
    float l2_1 = l3_0;
    float l2_2 = __fadd_rn(l3_0, s2t[2]);
    float l2_3 = P4;
    float l1_0 = fz ? s1t[0] : __fadd_rn(left, s1t[0]);
    float l1_1 = l2_0;
    float l1_2 = __fadd_rn(l2_0, s1t[2]);
    float l1_3 = l2_1;
    float l1_4 = __fadd_rn(l2_1, s1t[4]);
    float l1_5 = l2_2;
    float l1_6 = __fadd_rn(l2_2, s1t[6]);
    float l1_7 = l2_3;
    float ph[16];
    ph[0]  = fz ? v[0] : __fadd_rn(left, v[0]);
    ph[1]  = l1_0;
    ph[2]  = __fadd_rn(l1_0, v[2]);
    ph[3]  = l1_1;
    ph[4]  = __fadd_rn(l1_1, v[4]);
    ph[5]  = l1_2;
    ph[6]  = __fadd_rn(l1_2, v[6]);
    ph[7]  = l1_3;
    ph[8]  = __fadd_rn(l1_3, v[8]);
    ph[9]  = l1_4;
    ph[10] = __fadd_rn(l1_4, v[10]);
    ph[11] = l1_5;
    ph[12] = __fadd_rn(l1_5, v[12]);
    ph[13] = l1_6;
    ph[14] = __fadd_rn(l1_6, v[14]);
    ph[15] = l1_7;
    float ga0 = amp[((size_t)(b * NT + f)) * 64 + p];
    float ga1 = amp[((size_t)(b * NT + f1)) * 64 + p];
    float ga2 = amp[((size_t)(b * NT + f2)) * 64 + p];
#pragma unroll
    for (int t = 0; t < 16; ++t) {
      bool dn = (dnmask >> t) & 1;
      float fr = dn ? fs1 : fs0;
      if (fr < 22050.0f) {
        float x = __fmul_rn(ph[t], TWOPI_F);
        float s = sin_fast(x);
        bool d = (damask >> t) & 1;
        float lo = d ? ga1 : ga0;
        float hi = d ? ga2 : ga1;
        float au = __builtin_fmaf(__fsub_rn(hi, lo), wv[t], lo);
        acc[t] = __builtin_fmaf(s, au, acc[t]);
      }
    }
  }
  if (act) {
    size_t obase = ((size_t)g * NBATCH + b) * TAUD + (size_t)j0;
#pragma unroll
    for (int t = 0; t < 16; ++t) hpart[obase + t] = acc[t];
  }
}

// ---------------- circular convolution + final mix (fused, 8 hpart slices) ------
#define CT    1024
#define PSTR  392
__global__ __launch_bounds__(256) void k_convfinal(const float* __restrict__ noise,
                                                   const float* __restrict__ hh,
                                                   const float* __restrict__ hpart,
                                                   const float* __restrict__ loud,
                                                   float* __restrict__ out) {
  int b = blockIdx.y;
  int t0 = blockIdx.x * CT;
  int tid = threadIdx.x;
  __shared__ float xsp[4 * PSTR];     // window x[t0-256 .. t0+CT+256)
  __shared__ float hsh[LCONV];        // h[1..256]
  const float* hb = hh + b * (LCONV + 1);
  for (int i = tid; i < CT + 2 * LCONV; i += 256) {
    int j = t0 - LCONV + i;
    if (j < 0) j += TAUD;
    else if (j >= TAUD) j -= TAUD;
    xsp[(i & 3) * PSTR + (i >> 2)] = noise[(size_t)b * TAUD + j];
  }
  hsh[tid] = hb[1 + tid];             // LCONV == blockDim == 256
  __syncthreads();
  float h0 = hb[0];
  int B4 = tid + 64;                  // plane row of x[t0 + 4*tid]
  float a0 = h0 * xsp[0 * PSTR + B4];
  float a1 = h0 * xsp[1 * PSTR + B4];
  float a2 = h0 * xsp[2 * PSTR + B4];
  float a3 = h0 * xsp[3 * PSTR + B4];
  for (int g = 0; g < 32; ++g) {      // taps d = 8g+1 .. 8g+8
    int km = tid + 62 - 2 * g;        // minus side base (plane k)
    int kp = tid + 64 + 2 * g;        // plus side base
    float mv0 = xsp[0 * PSTR + km],     mv1 = xsp[1 * PSTR + km];
    float mv2 = xsp[2 * PSTR + km],     mv3 = xsp[3 * PSTR + km];
    float mv4 = xsp[0 * PSTR + km + 1], mv5 = xsp[1 * PSTR + km + 1];
    float mv6 = xsp[2 * PSTR + km + 1], mv7 = xsp[3 * PSTR + km + 1];
    float mv8 = xsp[0 * PSTR + km + 2], mv9 = xsp[1 * PSTR + km + 2];
    float mv10 = xsp[2 * PSTR + km + 2];
    float pv1 = xsp[1 * PSTR + kp],     pv2 = xsp[2 * PSTR + kp];
    float pv3 = xsp[3 * PSTR + kp];
    float pv4 = xsp[0 * PSTR + kp + 1], pv5 = xsp[1 * PSTR + kp + 1];
    float pv6 = xsp[2 * PSTR + kp + 1], pv7 = xsp[3 * PSTR + kp + 1];
    float pv8 = xsp[0 * PSTR + kp + 2], pv9 = xsp[1 * PSTR + kp + 2];
    float pv10 = xsp[2 * PSTR + kp + 2], pv11 = xsp[3 * PSTR + kp + 2];
    int hbase = 8 * g;                // uniform -> broadcast reads
    float hv0 = hsh[hbase + 0], hv1 = hsh[hbase + 1];
    float hv2 = hsh[hbase + 2], hv3 = hsh[hbase + 3];
    float hv4 = hsh[hbase + 4], hv5 = hsh[hbase + 5];
    float hv6 = hsh[hbase + 6], hv7 = hsh[hbase + 7];
    a0 = fmaf(hv0, mv7 + pv1, a0);
    a0 = fmaf(hv1, mv6 + pv2, a0);
    a0 = fmaf(hv2, mv5 + pv3, a0);
    a0 = fmaf(hv3, mv4 + pv4, a0);
    a0 = fmaf(hv4, mv3 + pv5, a0);
    a0 = fmaf(hv5, mv2 + pv6, a0);
    a0 = fmaf(hv6, mv1 + pv7, a0);
    a0 = fmaf(hv7, mv0 + pv8, a0);
    a1 = fmaf(hv0, mv8 + pv2, a1);
    a1 = fmaf(hv1, mv7 + pv3, a1);
    a1 = fmaf(hv2, mv6 + pv4, a1);
    a1 = fmaf(hv3, mv5 + pv5, a1);
    a1 = fmaf(hv4, mv4 + pv6, a1);
    a1 = fmaf(hv5, mv3 + pv7, a1);
    a1 = fmaf(hv6, mv2 + pv8, a1);
    a1 = fmaf(hv7, mv1 + pv9, a1);
    a2 = fmaf(hv0, mv9 + pv3, a2);
    a2 = fmaf(hv1, mv8 + pv4, a2);
    a2 = fmaf(hv2, mv7 + pv5, a2);
    a2 = fmaf(hv3, mv6 + pv6, a2);
    a2 = fmaf(hv4, mv5 + pv7, a2);
    a2 = fmaf(hv5, mv4 + pv8, a2);
    a2 = fmaf(hv6, mv3 + pv9, a2);
    a2 = fmaf(hv7, mv2 + pv10, a2);
    a3 = fmaf(hv0, mv10 + pv4, a3);
    a3 = fmaf(hv1, mv9 + pv5, a3);
    a3 = fmaf(hv2, mv8 + pv6, a3);
    a3 = fmaf(hv3, mv7 + pv7, a3);
    a3 = fmaf(hv4, mv6 + pv8, a3);
    a3 = fmaf(hv5, mv5 + pv9, a3);
    a3 = fmaf(hv6, mv4 + pv10, a3);
    a3 = fmaf(hv7, mv3 + pv11, a3);
  }
  int t = t0 + tid * 4;
  if (t < TAUD) {                     // TAUD%4==0 -> all 4 valid together
    const size_t S = (size_t)NBATCH * TAUD;
    size_t base = (size_t)b * TAUD + t;
    float hsum[4] = {0.0f, 0.0f, 0.0f, 0.0f};
#pragma unroll
    for (int sl = 0; sl < NPG; ++sl) {
      float4 hv = *(const float4*)&hpart[(size_t)sl * S + base];
      hsum[0] = __fadd_rn(hsum[0], hv.x);
      hsum[1] = __fadd_rn(hsum[1], hv.y);
      hsum[2] = __fadd_rn(hsum[2], hv.z);
      hsum[3] = __fadd_rn(hsum[3], hv.w);
    }
    float yn[4] = {a0 * 0.1f, a1 * 0.1f, a2 * 0.1f, a3 * 0.1f};
    float o[4];
#pragma unroll
    for (int u = 0; u < 4; ++u) {
      int j = t + u;
      int i0, i1; float w;
      iparams(j, i0, i1, w);
      float env = __fadd_rn(__fmul_rn(loud[b * NT + i0], __fsub_rn(1.0f, w)),
                            __fmul_rn(loud[b * NT + i1], w));
      o[u] = __fmul_rn(__fadd_rn(hsum[u], yn[u]), env);
    }
    *reinterpret_cast<float4*>(&out[base]) = make_float4(o[0], o[1], o[2], o[3]);
  }
}

}  // namespace

extern "C" void kernel_launch(void* const* d_in, const int* in_sizes, int n_in,
                              void* d_out, int out_size, void* d_ws, size_t ws_size,
                              hipStream_t stream) {
  const float* z    = (const float*)d_in[0];
  const float* f0n  = (const float*)d_in[1];
  const float* loud = (const float*)d_in[2];
  const float* nz   = (const float*)d_in[3];
  const float* W1p  = (const float*)d_in[4];
  const float* b1p  = (const float*)d_in[5];
  const float* W2p  = (const float*)d_in[6];
  const float* b2p  = (const float*)d_in[7];
  const float* W1n  = (const float*)d_in[8];
  const float* b1n  = (const float*)d_in[9];
  const float* W2n  = (const float*)d_in[10];
  const float* b2n  = (const float*)d_in[11];
  float* out = (float*)d_out;
  float* ws  = (float*)d_ws;

  size_t off = 0;
  float* amp    = ws + off; off += (size_t)NBATCH * NT * NPART;          // 256,000
  float* nmag   = ws + off; off += (size_t)NBATCH * NT * NBINS;          // 1,024,000
  float* mmpart = ws + off; off += (size_t)NBATCH * 10 * NBINS;          // 20,480
  float* G      = ws + off; off += (size_t)BSLC * (LCONV + 1) * NBINS;   // 526,336
  float* hh     = ws + off; off += (size_t)NBATCH * (LCONV + 1);         // 2,056
  float* lev4   = ws + off; off += (size_t)NBATCH * NPART * 5500;        // 2,816,000
  float* pref4  = ws + off; off += (size_t)NBATCH * NPART * 5500;        // 2,816,000
  float* hpart  = ws + off; off += (size_t)NPG * NBATCH * TAUD;          // 5,632,000
  (void)ws_size; (void)in_sizes; (void)n_in; (void)out_size;             // ~52 MB total

  // hp/hn alias hpart: consumed by k_mlp2 before k_harm overwrites hpart.
  float* hp = hpart;                      // 1,024,000 floats
  float* hn = hpart + (size_t)1024000;    // 1,024,000 floats (< 5,632,000)

  double HI = log2(2093.0), LO = log2(32.7);
  float C1 = (float)(HI - LO), C2 = (float)LO;

  dim3 gb(LCONV + 1, BSLC);
  k_basis<<<gb, 256, 0, stream>>>(G);
  dim3 g1(4, 125);
  k_mlp1<<<g1, 256, 0, stream>>>(z, W1p, b1p, W1n, b1n, hp, hn);
  dim3 g2(5, 125);
  k_mlp2<<<g2, 256, 0, stream>>>(hp, hn, W2p, b2p, W2n, b2n, amp, nmag);
  dim3 gm(NBATCH, 10);
  k_mean1<<<gm, 256, 0, stream>>>(nmag, mmpart);
  dim3 ghc(LCONV + 1, NBATCH);
  k_hc<<<ghc, 256, 0, stream>>>(mmpart, G, hh);
  dim3 gl(22, NBATCH, 4);
  k_lev4<<<gl, 256, 0, stream>>>(f0n, lev4, C1, C2);
  k_scan_rest<<<NBATCH * NPART, 256, 0, stream>>>(lev4, pref4);
  dim3 gh(22, NBATCH, NPG);
  k_harm<<<gh, 256, 0, stream>>>(f0n, amp, pref4, hpart, C1, C2);
  dim3 gc((TAUD + CT - 1) / CT, NBATCH);
  k_convfinal<<<gc, 256, 0, stream>>>(nz, hh, hpart, loud, out);
}